// Round 1
// baseline (3060.004 us; speedup 1.0000x reference)
//
#include <hip/hip_runtime.h>
#include <hip/hip_bf16.h>

#define NWAY 20
#define NSHOT 5
#define NQ 1000
#define NT 8
#define NDIM 640
#define NSEM 300
#define NSEMH 150
#define NCLS 351
#define NXY 121
#define NWT 160   // NWAY*NT, indexed wt = w*8 + t

__device__ __forceinline__ float sigmoidf_(float x) { return 1.0f / (1.0f + expf(-x)); }
__device__ __forceinline__ float lreluf_(float x) { return x >= 0.0f ? x : 0.1f * x; }
__device__ __forceinline__ float invl2_(float ss) { return 1.0f / fmaxf(sqrtf(ss), 1e-12f); }

__device__ __forceinline__ float waveReduceSum(float v) {
#pragma unroll
    for (int off = 32; off > 0; off >>= 1) v += __shfl_down(v, off, 64);
    return v;
}

// ---------------------------------------------------------------- k_filt
// h[t,w,d] = lrelu(sum_s l2v[w,s]*w1[t,d,s] + b1[t,d])
// filt[t,w,c] = sum_d h*w2[t,c,d] + b2[t,c]; filt_n = l2n over c.
// stored as filt_n[(w*8+t)*640 + c]
__global__ __launch_bounds__(256) void k_filt(const float* __restrict__ l2v,
    const float* __restrict__ w1, const float* __restrict__ b1,
    const float* __restrict__ w2, const float* __restrict__ b2,
    float* __restrict__ filt_n)
{
    int wt = blockIdx.x;
    int w = wt >> 3, t = wt & 7;
    int tid = threadIdx.x, lane = tid & 63, wv = tid >> 6;
    __shared__ float h_lds[NSEM];
    __shared__ float f_lds[NDIM];
    __shared__ float red[4];
    for (int j = 0; j < 75; ++j) {
        int d = wv * 75 + j;
        float acc = 0.f;
#pragma unroll
        for (int m = 0; m < 5; ++m) {
            int s = lane + 64 * m;
            if (s < NSEM) acc += l2v[w * NSEM + s] * w1[((size_t)t * NSEM + d) * NSEM + s];
        }
        acc = waveReduceSum(acc);
        if (lane == 0) h_lds[d] = lreluf_(acc + b1[t * NSEM + d]);
    }
    __syncthreads();
    for (int j = 0; j < 160; ++j) {
        int c = wv * 160 + j;
        float acc = 0.f;
#pragma unroll
        for (int m = 0; m < 5; ++m) {
            int d = lane + 64 * m;
            if (d < NSEM) acc += h_lds[d] * w2[((size_t)t * NDIM + c) * NSEM + d];
        }
        acc = waveReduceSum(acc);
        if (lane == 0) f_lds[c] = acc + b2[t * NDIM + c];
    }
    __syncthreads();
    float s = 0.f;
    for (int c = tid; c < NDIM; c += 256) s += f_lds[c] * f_lds[c];
    s = waveReduceSum(s);
    if (lane == 0) red[wv] = s;
    __syncthreads();
    float inv = invl2_(red[0] + red[1] + red[2] + red[3]);
    for (int c = tid; c < NDIM; c += 256) filt_n[(size_t)wt * NDIM + c] = f_lds[c] * inv;
}

// ---------------------------------------------------------------- k_wgt
__global__ __launch_bounds__(256) void k_wgt(const float* __restrict__ l2v,
    const float* __restrict__ wt1, const float* __restrict__ bt1,
    const float* __restrict__ wt2, const float* __restrict__ bt2,
    const float* __restrict__ tb, const float* __restrict__ tl1,
    const float* __restrict__ tl2, float* __restrict__ wgt)
{
    int w = blockIdx.x;
    int tid = threadIdx.x;
    __shared__ float h2[NSEMH];
    __shared__ float wl[NT];
    __shared__ float ssum;
    if (tid < NSEMH) {
        float acc = 0.f;
        for (int s = 0; s < NSEM; ++s) acc += l2v[w * NSEM + s] * wt1[tid * NSEM + s];
        h2[tid] = lreluf_(acc + bt1[tid]);
    }
    __syncthreads();
    if (tid < NT) {
        float acc = 0.f;
        for (int d = 0; d < NSEMH; ++d) acc += h2[d] * wt2[tid * NSEMH + d];
        float wg = sigmoidf_(acc + bt2[tid]);
        wl[tid] = tl1[0] * tl1[0] * sigmoidf_(tb[tid]) + tl2[0] * tl2[0] * wg;
    }
    __syncthreads();
    if (tid == 0) { float s2 = 0.f; for (int t = 0; t < NT; ++t) s2 += wl[t]; ssum = s2; }
    __syncthreads();
    if (tid < NT) wgt[w * NT + tid] = wl[tid] / ssum;
}

// ---------------------------------------------------------------- k_rownorm
// rows 0..2807: weight_base [k][t][640] -> wbn ; rows 2808..: wkeys [t][k][640] -> wkn
__global__ __launch_bounds__(128) void k_rownorm(const float* __restrict__ wb,
    const float* __restrict__ wk, float* __restrict__ wbn, float* __restrict__ wkn)
{
    int r = blockIdx.x;
    const float* src; float* dst;
    if (r < NCLS * NT) { src = wb + (size_t)r * NDIM; dst = wbn + (size_t)r * NDIM; }
    else { int r2 = r - NCLS * NT; src = wk + (size_t)r2 * NDIM; dst = wkn + (size_t)r2 * NDIM; }
    int tid = threadIdx.x, lane = tid & 63, wv = tid >> 6;
    __shared__ float red[2];
    float v[5]; float ss = 0.f;
#pragma unroll
    for (int m = 0; m < 5; ++m) { v[m] = src[tid + 128 * m]; ss += v[m] * v[m]; }
    ss = waveReduceSum(ss);
    if (lane == 0) red[wv] = ss;
    __syncthreads();
    float inv = invl2_(red[0] + red[1]);
#pragma unroll
    for (int m = 0; m < 5; ++m) dst[tid + 128 * m] = v[m] * inv;
}

// ---------------------------------------------------------------- k_support
// one block per (w,s) image: act' then pooled spt_tn[(n*8+t)*640+c]
__global__ __launch_bounds__(128) void k_support(const float* __restrict__ spt,
    const float* __restrict__ filt_n, float* __restrict__ spt_tn)
{
    int w = blockIdx.x, s = blockIdx.y;
    int n = s * NWAY + w;
    int tid = threadIdx.x, lane = tid & 63, wv = tid >> 6;
    const float* base = spt + (size_t)n * NDIM * NXY;
    const float* fw = filt_n + (size_t)(w * NT) * NDIM;
    __shared__ float actT[128][NT];
    __shared__ float sT[8][648];
    __shared__ float red[16];
    __shared__ float invt[NT];
    {
        float acc[NT] = {0, 0, 0, 0, 0, 0, 0, 0};
        float ssq = 0.f;
        int xy = tid;
        if (xy < NXY) {
            for (int c = 0; c < NDIM; ++c) {
                float qv = base[c * NXY + xy];
                ssq += qv * qv;
#pragma unroll
                for (int t = 0; t < NT; ++t) acc[t] += qv * fw[t * NDIM + c];
            }
            float inv = invl2_(ssq);
#pragma unroll
            for (int t = 0; t < NT; ++t) actT[xy][t] = sigmoidf_(acc[t] * inv) * inv;
        }
    }
    __syncthreads();
    float qt[5][NT];
#pragma unroll
    for (int k = 0; k < 5; ++k)
#pragma unroll
        for (int t = 0; t < NT; ++t) qt[k][t] = 0.f;
    for (int xy0 = 0; xy0 < NXY; xy0 += 8) {
        int nxy = min(8, NXY - xy0);
        __syncthreads();
        for (int idx = tid; idx < 8 * NDIM; idx += 128) {
            int c = idx >> 3, xyl = idx & 7;
            sT[xyl][c] = (xy0 + xyl < NXY) ? base[c * NXY + xy0 + xyl] : 0.f;
        }
        __syncthreads();
        for (int j = 0; j < nxy; ++j) {
            float av[NT];
#pragma unroll
            for (int t = 0; t < NT; ++t) av[t] = actT[xy0 + j][t];
#pragma unroll
            for (int k = 0; k < 5; ++k) {
                float qv = sT[j][tid + (k << 7)];
#pragma unroll
                for (int t = 0; t < NT; ++t) qt[k][t] += qv * av[t];
            }
        }
    }
    float lss[NT];
#pragma unroll
    for (int t = 0; t < NT; ++t) lss[t] = 0.f;
#pragma unroll
    for (int k = 0; k < 5; ++k)
#pragma unroll
        for (int t = 0; t < NT; ++t) lss[t] += qt[k][t] * qt[k][t];
#pragma unroll
    for (int t = 0; t < NT; ++t) {
        float v = waveReduceSum(lss[t]);
        if (lane == 0) red[wv * NT + t] = v;
    }
    __syncthreads();
    if (tid < NT) invt[tid] = invl2_(red[tid] + red[NT + tid]);
    __syncthreads();
#pragma unroll
    for (int k = 0; k < 5; ++k) {
        int c = tid + (k << 7);
#pragma unroll
        for (int t = 0; t < NT; ++t)
            spt_tn[((size_t)n * NT + t) * NDIM + c] = qt[k][t] * invt[t];
    }
}

// ---------------------------------------------------------------- k_weight
// per (n,t): qe = l2n(wq[t]@x + bq[t]); att = softmax(scale * qe.wk_n); wtb = att.wb_n
// comb = ln^2 * x + lb^2 * wtb
__global__ __launch_bounds__(256) void k_weight(const float* __restrict__ spt_tn,
    const float* __restrict__ wq, const float* __restrict__ bq,
    const float* __restrict__ wkn, const float* __restrict__ wbn,
    const float* __restrict__ scale_att, const float* __restrict__ lam_n,
    const float* __restrict__ lam_b, float* __restrict__ comb)
{
    int bid = blockIdx.x;
    int n = bid >> 3, t = bid & 7;
    int tid = threadIdx.x, lane = tid & 63, wv = tid >> 6;
    __shared__ float x[NDIM];
    __shared__ float qe[NDIM];
    __shared__ float sc[NCLS];
    __shared__ float red[4];
    __shared__ float bc[2];
    for (int c = tid; c < NDIM; c += 256) x[c] = spt_tn[((size_t)n * NT + t) * NDIM + c];
    __syncthreads();
    const float* wqt = wq + (size_t)t * NDIM * NDIM;
    for (int j = 0; j < 160; ++j) {
        int d = wv * 160 + j;
        float acc = 0.f;
#pragma unroll
        for (int m = 0; m < 10; ++m) {
            int c = lane + 64 * m;
            acc += x[c] * wqt[(size_t)d * NDIM + c];
        }
        acc = waveReduceSum(acc);
        if (lane == 0) qe[d] = acc + bq[t * NDIM + d];
    }
    __syncthreads();
    {
        float s = 0.f;
        for (int d = tid; d < NDIM; d += 256) s += qe[d] * qe[d];
        s = waveReduceSum(s);
        if (lane == 0) red[wv] = s;
    }
    __syncthreads();
    {
        float inv = invl2_(red[0] + red[1] + red[2] + red[3]);
        for (int d = tid; d < NDIM; d += 256) qe[d] *= inv;
    }
    __syncthreads();
    const float* wkt = wkn + (size_t)t * NCLS * NDIM;
    float sat = scale_att[t];
    for (int j = 0; j < 88; ++j) {
        int k = wv * 88 + j;
        if (k < NCLS) {
            float acc = 0.f;
#pragma unroll
            for (int m = 0; m < 10; ++m) {
                int d = lane + 64 * m;
                acc += qe[d] * wkt[(size_t)k * NDIM + d];
            }
            acc = waveReduceSum(acc);
            if (lane == 0) sc[k] = sat * acc;
        }
    }
    __syncthreads();
    {
        float mx = -1e30f;
        for (int k = tid; k < NCLS; k += 256) mx = fmaxf(mx, sc[k]);
#pragma unroll
        for (int off = 32; off > 0; off >>= 1) mx = fmaxf(mx, __shfl_down(mx, off, 64));
        if (lane == 0) red[wv] = mx;
        __syncthreads();
        if (tid == 0) bc[0] = fmaxf(fmaxf(red[0], red[1]), fmaxf(red[2], red[3]));
        __syncthreads();
        float gm = bc[0];
        float s = 0.f;
        for (int k = tid; k < NCLS; k += 256) { float e = expf(sc[k] - gm); sc[k] = e; s += e; }
        s = waveReduceSum(s);
        if (lane == 0) red[wv] = s;
        __syncthreads();
        if (tid == 0) bc[1] = red[0] + red[1] + red[2] + red[3];
        __syncthreads();
        float invs = 1.0f / bc[1];
        for (int k = tid; k < NCLS; k += 256) sc[k] *= invs;
    }
    __syncthreads();
    float ln2 = lam_n[t] * lam_n[t], lb2 = lam_b[t] * lam_b[t];
    float wacc[3] = {0.f, 0.f, 0.f};
    for (int k = 0; k < NCLS; ++k) {
        float sv = sc[k];
        const float* wrow = wbn + ((size_t)k * NT + t) * NDIM;
#pragma unroll
        for (int m = 0; m < 3; ++m) {
            int c = tid + 256 * m;
            if (c < NDIM) wacc[m] += sv * wrow[c];
        }
    }
#pragma unroll
    for (int m = 0; m < 3; ++m) {
        int c = tid + 256 * m;
        if (c < NDIM) comb[((size_t)n * NT + t) * NDIM + c] = ln2 * x[c] + lb2 * wacc[m];
    }
}

// ---------------------------------------------------------------- k_proto
__global__ __launch_bounds__(128) void k_proto(const float* __restrict__ comb,
    float* __restrict__ proto)
{
    int wt = blockIdx.x;
    int w = wt >> 3, t = wt & 7;
    int tid = threadIdx.x, lane = tid & 63, wv = tid >> 6;
    __shared__ float red[2];
    float mv[5]; float ss = 0.f;
#pragma unroll
    for (int m = 0; m < 5; ++m) {
        int c = tid + 128 * m;
        float a = 0.f;
#pragma unroll
        for (int s = 0; s < NSHOT; ++s)
            a += comb[(((size_t)(s * NWAY + w)) * NT + t) * NDIM + c];
        a *= 0.2f;
        mv[m] = a; ss += a * a;
    }
    ss = waveReduceSum(ss);
    if (lane == 0) red[wv] = ss;
    __syncthreads();
    float inv = invl2_(red[0] + red[1]);
#pragma unroll
    for (int m = 0; m < 5; ++m) proto[(size_t)wt * NDIM + tid + 128 * m] = mv[m] * inv;
}

// ---------------------------------------------------------------- k_act
// per q: act'[xy][wt] = sigmoid(inv[xy]*dot(qry[:,xy],filt[wt,:])) * inv[xy]
#define ACT_CC 32
__global__ __launch_bounds__(320) void k_act(const float* __restrict__ qry,
    const float* __restrict__ filt_n, float* __restrict__ act_ws)
{
    int q = blockIdx.x;
    int tid = threadIdx.x;
    const float* base = qry + (size_t)q * NDIM * NXY;
    __shared__ float qc[ACT_CC][128];
    __shared__ float fT[ACT_CC][164];
    __shared__ float invl[128];
    __shared__ float red[2][128];
    if (tid < 256) {
        int xy = tid & 127, part = tid >> 7;
        float ss = 0.f;
        if (xy < NXY) {
            for (int c = part; c < NDIM; c += 2) {
                float v = base[c * NXY + xy];
                ss += v * v;
            }
        }
        red[part][xy] = ss;
    }
    __syncthreads();
    if (tid < 128) invl[tid] = invl2_(red[0][tid] + red[1][tid]);
    float acc[8][8];
#pragma unroll
    for (int i = 0; i < 8; ++i)
#pragma unroll
        for (int j = 0; j < 8; ++j) acc[i][j] = 0.f;
    int wtg = tid / 16, xyg = tid & 15;
    int wt0 = wtg * 8, xy0 = xyg * 8;
    for (int c0 = 0; c0 < NDIM; c0 += ACT_CC) {
        __syncthreads();
        for (int idx = tid; idx < ACT_CC * 128; idx += 320) {
            int ci = idx >> 7, xy = idx & 127;
            qc[ci][xy] = (xy < NXY) ? base[(c0 + ci) * NXY + xy] : 0.f;
        }
        for (int idx = tid; idx < ACT_CC * NWT; idx += 320) {
            int c = idx & (ACT_CC - 1), wt = idx >> 5;
            fT[c][wt] = filt_n[(size_t)wt * NDIM + c0 + c];
        }
        __syncthreads();
        for (int cc = 0; cc < ACT_CC; ++cc) {
            float fv[8], qv[8];
#pragma unroll
            for (int i = 0; i < 8; ++i) fv[i] = fT[cc][wt0 + i];
#pragma unroll
            for (int j = 0; j < 8; ++j) qv[j] = qc[cc][xy0 + j];
#pragma unroll
            for (int i = 0; i < 8; ++i)
#pragma unroll
                for (int j = 0; j < 8; ++j) acc[i][j] += fv[i] * qv[j];
        }
    }
#pragma unroll
    for (int j = 0; j < 8; ++j) {
        int xy = xy0 + j;
        if (xy < NXY) {
            float inv = invl[xy];
            float* dst = act_ws + ((size_t)q * NXY + xy) * NWT + wt0;
#pragma unroll
            for (int i = 0; i < 8; ++i) dst[i] = sigmoidf_(acc[i][j] * inv) * inv;
        }
    }
}

// ---------------------------------------------------------------- k_pool
// per (ctile,q): qry_t[wt][c] = sum_xy qry[c,xy]*act'[xy][wt]; emit partial dot/ss
__global__ __launch_bounds__(320) void k_pool(const float* __restrict__ qry,
    const float* __restrict__ act_ws, const float* __restrict__ proto,
    float* __restrict__ partial)
{
    int ct = blockIdx.x, q = blockIdx.y;
    int c0 = ct * 128;
    int tid = threadIdx.x;
    int wtg = tid / 16, cg = tid & 15;
    int wt0 = wtg * 8;
    const float* base = qry + (size_t)q * NDIM * NXY;
    __shared__ float qT[16][136];
    __shared__ float aT[16][164];
    float acc[8][8];
#pragma unroll
    for (int i = 0; i < 8; ++i)
#pragma unroll
        for (int j = 0; j < 8; ++j) acc[i][j] = 0.f;
    for (int xy0 = 0; xy0 < NXY; xy0 += 16) {
        int nxy = min(16, NXY - xy0);
        __syncthreads();
        for (int idx = tid; idx < 16 * 128; idx += 320) {
            int ci = idx >> 4, xyl = idx & 15;
            qT[xyl][ci] = (xy0 + xyl < NXY) ? base[(c0 + ci) * NXY + xy0 + xyl] : 0.f;
        }
        for (int idx = tid; idx < nxy * NWT; idx += 320) {
            int xyl = idx / NWT, wt = idx - xyl * NWT;
            aT[xyl][wt] = act_ws[((size_t)q * NXY + xy0 + xyl) * NWT + wt];
        }
        __syncthreads();
        for (int j = 0; j < nxy; ++j) {
            float av[8], qv[8];
#pragma unroll
            for (int i = 0; i < 8; ++i) av[i] = aT[j][wt0 + i];
#pragma unroll
            for (int jj = 0; jj < 8; ++jj) qv[jj] = qT[j][cg * 8 + jj];
#pragma unroll
            for (int i = 0; i < 8; ++i)
#pragma unroll
                for (int jj = 0; jj < 8; ++jj) acc[i][jj] += av[i] * qv[jj];
        }
    }
    float dots[8], sss[8];
#pragma unroll
    for (int i = 0; i < 8; ++i) {
        int wt = wt0 + i;
        const float* pw = proto + (size_t)wt * NDIM + c0 + cg * 8;
        float d = 0.f, ssq = 0.f;
#pragma unroll
        for (int jj = 0; jj < 8; ++jj) { d += acc[i][jj] * pw[jj]; ssq += acc[i][jj] * acc[i][jj]; }
#pragma unroll
        for (int off = 1; off < 16; off <<= 1) { d += __shfl_xor(d, off, 64); ssq += __shfl_xor(ssq, off, 64); }
        dots[i] = d; sss[i] = ssq;
    }
    if (cg == 0) {
        float* p = partial + (((size_t)q * 5 + ct) * NWT + wt0) * 2;
#pragma unroll
        for (int i = 0; i < 8; ++i) { p[2 * i] = dots[i]; p[2 * i + 1] = sss[i]; }
    }
}

// ---------------------------------------------------------------- k_final
__global__ __launch_bounds__(256) void k_final(const float* __restrict__ partial,
    const float* __restrict__ wgt, float* __restrict__ out)
{
    int q = blockIdx.x;
    int tid = threadIdx.x;
    __shared__ float sim[NWT];
    if (tid < NWT) {
        float d = 0.f, s = 0.f;
#pragma unroll
        for (int ct = 0; ct < 5; ++ct) {
            const float* p = partial + (((size_t)q * 5 + ct) * NWT + tid) * 2;
            d += p[0]; s += p[1];
        }
        sim[tid] = d * invl2_(s);
    }
    __syncthreads();
    if (tid < NWAY) {
        float lg = 0.f;
#pragma unroll
        for (int t = 0; t < NT; ++t) lg += sim[tid * NT + t] * wgt[tid * NT + t];
        out[q * NWAY + tid] = lg * 2.0f;   // / TEMP (0.5)
    }
}

extern "C" void kernel_launch(void* const* d_in, const int* in_sizes, int n_in,
                              void* d_out, int out_size, void* d_ws, size_t ws_size,
                              hipStream_t stream)
{
    const float* spt  = (const float*)d_in[0];
    const float* qry  = (const float*)d_in[1];
    const float* l2v  = (const float*)d_in[2];
    const float* w1   = (const float*)d_in[3];
    const float* b1   = (const float*)d_in[4];
    const float* w2   = (const float*)d_in[5];
    const float* b2   = (const float*)d_in[6];
    const float* wb   = (const float*)d_in[7];
    const float* wq   = (const float*)d_in[8];
    const float* bq   = (const float*)d_in[9];
    const float* wk   = (const float*)d_in[10];
    const float* sat  = (const float*)d_in[11];
    const float* lamn = (const float*)d_in[12];
    const float* lamb = (const float*)d_in[13];
    const float* wt1  = (const float*)d_in[14];
    const float* bt1  = (const float*)d_in[15];
    const float* wt2  = (const float*)d_in[16];
    const float* bt2  = (const float*)d_in[17];
    const float* tb   = (const float*)d_in[18];
    const float* tl1  = (const float*)d_in[19];
    const float* tl2  = (const float*)d_in[20];

    float* ws    = (float*)d_ws;
    float* filt  = ws;                       // 160*640      = 102400
    float* wgt   = filt + 102400;            // 160
    float* wbn   = wgt + 160;                // 2808*640     = 1797120
    float* wkn   = wbn + 1797120;            // 1797120
    float* sptn  = wkn + 1797120;            // 100*8*640    = 512000
    float* combv = sptn + 512000;            // 512000
    float* proto = combv + 512000;           // 102400
    float* actw  = proto + 102400;           // 1000*121*160 = 19360000
    float* part  = actw + 19360000;          // 1000*5*160*2 = 1600000
    float* outp  = (float*)d_out;

    hipLaunchKernelGGL(k_filt,    dim3(160),      dim3(256), 0, stream, l2v, w1, b1, w2, b2, filt);
    hipLaunchKernelGGL(k_wgt,     dim3(20),       dim3(256), 0, stream, l2v, wt1, bt1, wt2, bt2, tb, tl1, tl2, wgt);
    hipLaunchKernelGGL(k_rownorm, dim3(2808 * 2), dim3(128), 0, stream, wb, wk, wbn, wkn);
    hipLaunchKernelGGL(k_support, dim3(20, 5),    dim3(128), 0, stream, spt, filt, sptn);
    hipLaunchKernelGGL(k_weight,  dim3(800),      dim3(256), 0, stream, sptn, wq, bq, wkn, wbn, sat, lamn, lamb, combv);
    hipLaunchKernelGGL(k_proto,   dim3(160),      dim3(128), 0, stream, combv, proto);
    hipLaunchKernelGGL(k_act,     dim3(1000),     dim3(320), 0, stream, qry, filt, actw);
    hipLaunchKernelGGL(k_pool,    dim3(5, 1000),  dim3(320), 0, stream, qry, actw, proto, part);
    hipLaunchKernelGGL(k_final,   dim3(1000),     dim3(256), 0, stream, part, wgt, outp);
}

// Round 2
// 1360.019 us; speedup vs baseline: 2.2500x; 2.2500x over previous
//
#include <hip/hip_runtime.h>
#include <hip/hip_bf16.h>

#define NWAY 20
#define NSHOT 5
#define NT 8
#define NDIM 640
#define NSEM 300
#define NSEMH 150
#define NCLS 351
#define NXY 121
#define NWT 160   // NWAY*NT, indexed wt = w*8 + t

typedef short s16x8 __attribute__((ext_vector_type(8)));
typedef float f32x4 __attribute__((ext_vector_type(4)));

__device__ __forceinline__ float sigmoidf_(float x) { return 1.0f / (1.0f + expf(-x)); }
__device__ __forceinline__ float lreluf_(float x) { return x >= 0.0f ? x : 0.1f * x; }
__device__ __forceinline__ float invl2_(float ss) { return 1.0f / fmaxf(sqrtf(ss), 1e-12f); }

__device__ __forceinline__ unsigned bfr_(float f) {
    unsigned b = __float_as_uint(f);
    return (b + 0x7FFFu + ((b >> 16) & 1u)) >> 16;   // RNE to bf16
}
__device__ __forceinline__ unsigned pkbf_(float a, float b) { return bfr_(a) | (bfr_(b) << 16); }

__device__ __forceinline__ float waveReduceSum(float v) {
#pragma unroll
    for (int off = 32; off > 0; off >>= 1) v += __shfl_down(v, off, 64);
    return v;
}

// ---------------------------------------------------------------- k_filt
__global__ __launch_bounds__(256) void k_filt(const float* __restrict__ l2v,
    const float* __restrict__ w1, const float* __restrict__ b1,
    const float* __restrict__ w2, const float* __restrict__ b2,
    float* __restrict__ filt_n, ushort* __restrict__ filtb)
{
    int wt = blockIdx.x;
    int w = wt >> 3, t = wt & 7;
    int tid = threadIdx.x, lane = tid & 63, wv = tid >> 6;
    __shared__ float h_lds[NSEM];
    __shared__ float f_lds[NDIM];
    __shared__ float red[4];
    for (int j = 0; j < 75; ++j) {
        int d = wv * 75 + j;
        float acc = 0.f;
#pragma unroll
        for (int m = 0; m < 5; ++m) {
            int s = lane + 64 * m;
            if (s < NSEM) acc += l2v[w * NSEM + s] * w1[((size_t)t * NSEM + d) * NSEM + s];
        }
        acc = waveReduceSum(acc);
        if (lane == 0) h_lds[d] = lreluf_(acc + b1[t * NSEM + d]);
    }
    __syncthreads();
    for (int j = 0; j < 160; ++j) {
        int c = wv * 160 + j;
        float acc = 0.f;
#pragma unroll
        for (int m = 0; m < 5; ++m) {
            int d = lane + 64 * m;
            if (d < NSEM) acc += h_lds[d] * w2[((size_t)t * NDIM + c) * NSEM + d];
        }
        acc = waveReduceSum(acc);
        if (lane == 0) f_lds[c] = acc + b2[t * NDIM + c];
    }
    __syncthreads();
    float s = 0.f;
    for (int c = tid; c < NDIM; c += 256) s += f_lds[c] * f_lds[c];
    s = waveReduceSum(s);
    if (lane == 0) red[wv] = s;
    __syncthreads();
    float inv = invl2_(red[0] + red[1] + red[2] + red[3]);
    for (int c = tid; c < NDIM; c += 256) {
        float v = f_lds[c] * inv;
        filt_n[(size_t)wt * NDIM + c] = v;
        filtb[(size_t)wt * NDIM + c] = (ushort)bfr_(v);
    }
}

// ---------------------------------------------------------------- k_wgt
__global__ __launch_bounds__(256) void k_wgt(const float* __restrict__ l2v,
    const float* __restrict__ wt1, const float* __restrict__ bt1,
    const float* __restrict__ wt2, const float* __restrict__ bt2,
    const float* __restrict__ tb, const float* __restrict__ tl1,
    const float* __restrict__ tl2, float* __restrict__ wgt)
{
    int w = blockIdx.x;
    int tid = threadIdx.x;
    __shared__ float h2[NSEMH];
    __shared__ float wl[NT];
    __shared__ float ssum;
    if (tid < NSEMH) {
        float acc = 0.f;
        for (int s = 0; s < NSEM; ++s) acc += l2v[w * NSEM + s] * wt1[tid * NSEM + s];
        h2[tid] = lreluf_(acc + bt1[tid]);
    }
    __syncthreads();
    if (tid < NT) {
        float acc = 0.f;
        for (int d = 0; d < NSEMH; ++d) acc += h2[d] * wt2[tid * NSEMH + d];
        float wg = sigmoidf_(acc + bt2[tid]);
        wl[tid] = tl1[0] * tl1[0] * sigmoidf_(tb[tid]) + tl2[0] * tl2[0] * wg;
    }
    __syncthreads();
    if (tid == 0) { float s2 = 0.f; for (int t = 0; t < NT; ++t) s2 += wl[t]; ssum = s2; }
    __syncthreads();
    if (tid < NT) wgt[w * NT + tid] = wl[tid] / ssum;
}

// ---------------------------------------------------------------- k_rownorm
__global__ __launch_bounds__(128) void k_rownorm(const float* __restrict__ wb,
    const float* __restrict__ wk, float* __restrict__ wbn, float* __restrict__ wkn)
{
    int r = blockIdx.x;
    const float* src; float* dst;
    if (r < NCLS * NT) { src = wb + (size_t)r * NDIM; dst = wbn + (size_t)r * NDIM; }
    else { int r2 = r - NCLS * NT; src = wk + (size_t)r2 * NDIM; dst = wkn + (size_t)r2 * NDIM; }
    int tid = threadIdx.x, lane = tid & 63, wv = tid >> 6;
    __shared__ float red[2];
    float v[5]; float ss = 0.f;
#pragma unroll
    for (int m = 0; m < 5; ++m) { v[m] = src[tid + 128 * m]; ss += v[m] * v[m]; }
    ss = waveReduceSum(ss);
    if (lane == 0) red[wv] = ss;
    __syncthreads();
    float inv = invl2_(red[0] + red[1]);
#pragma unroll
    for (int m = 0; m < 5; ++m) dst[tid + 128 * m] = v[m] * inv;
}

// ---------------------------------------------------------------- k_support
__global__ __launch_bounds__(128) void k_support(const float* __restrict__ spt,
    const float* __restrict__ filt_n, float* __restrict__ spt_tn)
{
    int w = blockIdx.x, s = blockIdx.y;
    int n = s * NWAY + w;
    int tid = threadIdx.x, lane = tid & 63, wv = tid >> 6;
    const float* base = spt + (size_t)n * NDIM * NXY;
    const float* fw = filt_n + (size_t)(w * NT) * NDIM;
    __shared__ float actT[128][NT];
    __shared__ float sT[8][648];
    __shared__ float red[16];
    __shared__ float invt[NT];
    {
        float acc[NT] = {0, 0, 0, 0, 0, 0, 0, 0};
        float ssq = 0.f;
        int xy = tid;
        if (xy < NXY) {
            for (int c = 0; c < NDIM; ++c) {
                float qv = base[c * NXY + xy];
                ssq += qv * qv;
#pragma unroll
                for (int t = 0; t < NT; ++t) acc[t] += qv * fw[t * NDIM + c];
            }
            float inv = invl2_(ssq);
#pragma unroll
            for (int t = 0; t < NT; ++t) actT[xy][t] = sigmoidf_(acc[t] * inv) * inv;
        }
    }
    __syncthreads();
    float qt[5][NT];
#pragma unroll
    for (int k = 0; k < 5; ++k)
#pragma unroll
        for (int t = 0; t < NT; ++t) qt[k][t] = 0.f;
    for (int xy0 = 0; xy0 < NXY; xy0 += 8) {
        int nxy = min(8, NXY - xy0);
        __syncthreads();
        for (int idx = tid; idx < 8 * NDIM; idx += 128) {
            int c = idx >> 3, xyl = idx & 7;
            sT[xyl][c] = (xy0 + xyl < NXY) ? base[c * NXY + xy0 + xyl] : 0.f;
        }
        __syncthreads();
        for (int j = 0; j < nxy; ++j) {
            float av[NT];
#pragma unroll
            for (int t = 0; t < NT; ++t) av[t] = actT[xy0 + j][t];
#pragma unroll
            for (int k = 0; k < 5; ++k) {
                float qv = sT[j][tid + (k << 7)];
#pragma unroll
                for (int t = 0; t < NT; ++t) qt[k][t] += qv * av[t];
            }
        }
    }
    float lss[NT];
#pragma unroll
    for (int t = 0; t < NT; ++t) lss[t] = 0.f;
#pragma unroll
    for (int k = 0; k < 5; ++k)
#pragma unroll
        for (int t = 0; t < NT; ++t) lss[t] += qt[k][t] * qt[k][t];
#pragma unroll
    for (int t = 0; t < NT; ++t) {
        float v = waveReduceSum(lss[t]);
        if (lane == 0) red[wv * NT + t] = v;
    }
    __syncthreads();
    if (tid < NT) invt[tid] = invl2_(red[tid] + red[NT + tid]);
    __syncthreads();
#pragma unroll
    for (int k = 0; k < 5; ++k) {
        int c = tid + (k << 7);
#pragma unroll
        for (int t = 0; t < NT; ++t)
            spt_tn[((size_t)n * NT + t) * NDIM + c] = qt[k][t] * invt[t];
    }
}

// ---------------------------------------------------------------- k_weight
__global__ __launch_bounds__(256) void k_weight(const float* __restrict__ spt_tn,
    const float* __restrict__ wq, const float* __restrict__ bq,
    const float* __restrict__ wkn, const float* __restrict__ wbn,
    const float* __restrict__ scale_att, const float* __restrict__ lam_n,
    const float* __restrict__ lam_b, float* __restrict__ comb)
{
    int bid = blockIdx.x;
    int n = bid >> 3, t = bid & 7;
    int tid = threadIdx.x, lane = tid & 63, wv = tid >> 6;
    __shared__ float x[NDIM];
    __shared__ float qe[NDIM];
    __shared__ float sc[NCLS];
    __shared__ float red[4];
    __shared__ float bc[2];
    for (int c = tid; c < NDIM; c += 256) x[c] = spt_tn[((size_t)n * NT + t) * NDIM + c];
    __syncthreads();
    const float* wqt = wq + (size_t)t * NDIM * NDIM;
    for (int j = 0; j < 160; ++j) {
        int d = wv * 160 + j;
        float acc = 0.f;
#pragma unroll
        for (int m = 0; m < 10; ++m) {
            int c = lane + 64 * m;
            acc += x[c] * wqt[(size_t)d * NDIM + c];
        }
        acc = waveReduceSum(acc);
        if (lane == 0) qe[d] = acc + bq[t * NDIM + d];
    }
    __syncthreads();
    {
        float s = 0.f;
        for (int d = tid; d < NDIM; d += 256) s += qe[d] * qe[d];
        s = waveReduceSum(s);
        if (lane == 0) red[wv] = s;
    }
    __syncthreads();
    {
        float inv = invl2_(red[0] + red[1] + red[2] + red[3]);
        for (int d = tid; d < NDIM; d += 256) qe[d] *= inv;
    }
    __syncthreads();
    const float* wkt = wkn + (size_t)t * NCLS * NDIM;
    float sat = scale_att[t];
    for (int j = 0; j < 88; ++j) {
        int k = wv * 88 + j;
        if (k < NCLS) {
            float acc = 0.f;
#pragma unroll
            for (int m = 0; m < 10; ++m) {
                int d = lane + 64 * m;
                acc += qe[d] * wkt[(size_t)k * NDIM + d];
            }
            acc = waveReduceSum(acc);
            if (lane == 0) sc[k] = sat * acc;
        }
    }
    __syncthreads();
    {
        float mx = -1e30f;
        for (int k = tid; k < NCLS; k += 256) mx = fmaxf(mx, sc[k]);
#pragma unroll
        for (int off = 32; off > 0; off >>= 1) mx = fmaxf(mx, __shfl_down(mx, off, 64));
        if (lane == 0) red[wv] = mx;
        __syncthreads();
        if (tid == 0) bc[0] = fmaxf(fmaxf(red[0], red[1]), fmaxf(red[2], red[3]));
        __syncthreads();
        float gm = bc[0];
        float s = 0.f;
        for (int k = tid; k < NCLS; k += 256) { float e = expf(sc[k] - gm); sc[k] = e; s += e; }
        s = waveReduceSum(s);
        if (lane == 0) red[wv] = s;
        __syncthreads();
        if (tid == 0) bc[1] = red[0] + red[1] + red[2] + red[3];
        __syncthreads();
        float invs = 1.0f / bc[1];
        for (int k = tid; k < NCLS; k += 256) sc[k] *= invs;
    }
    __syncthreads();
    float ln2 = lam_n[t] * lam_n[t], lb2 = lam_b[t] * lam_b[t];
    float wacc[3] = {0.f, 0.f, 0.f};
    for (int k = 0; k < NCLS; ++k) {
        float sv = sc[k];
        const float* wrow = wbn + ((size_t)k * NT + t) * NDIM;
#pragma unroll
        for (int m = 0; m < 3; ++m) {
            int c = tid + 256 * m;
            if (c < NDIM) wacc[m] += sv * wrow[c];
        }
    }
#pragma unroll
    for (int m = 0; m < 3; ++m) {
        int c = tid + 256 * m;
        if (c < NDIM) comb[((size_t)n * NT + t) * NDIM + c] = ln2 * x[c] + lb2 * wacc[m];
    }
}

// ---------------------------------------------------------------- k_proto
__global__ __launch_bounds__(128) void k_proto(const float* __restrict__ comb,
    float* __restrict__ proto)
{
    int wt = blockIdx.x;
    int w = wt >> 3, t = wt & 7;
    int tid = threadIdx.x, lane = tid & 63, wv = tid >> 6;
    __shared__ float red[2];
    float mv[5]; float ss = 0.f;
#pragma unroll
    for (int m = 0; m < 5; ++m) {
        int c = tid + 128 * m;
        float a = 0.f;
#pragma unroll
        for (int s = 0; s < NSHOT; ++s)
            a += comb[(((size_t)(s * NWAY + w)) * NT + t) * NDIM + c];
        a *= 0.2f;
        mv[m] = a; ss += a * a;
    }
    ss = waveReduceSum(ss);
    if (lane == 0) red[wv] = ss;
    __syncthreads();
    float inv = invl2_(red[0] + red[1]);
#pragma unroll
    for (int m = 0; m < 5; ++m) proto[(size_t)wt * NDIM + tid + 128 * m] = mv[m] * inv;
}

// ---------------------------------------------------------------- k_query
// Fused act + pool + sim + logits, bf16 MFMA. One block per query image.
// Phase 1: S[wt][xy] = filt_bf16[160x640] x qryT (staged LDS) -> act (LDS bf16)
// Phase 2: qry_t[wt][c] = act x qryN (staged LDS); fold proto-dot + ssq epilogue.
__global__ __launch_bounds__(512, 1) void k_query(const float* __restrict__ qry,
    const ushort* __restrict__ filtb, const float* __restrict__ proto,
    const float* __restrict__ wgt, float* __restrict__ out)
{
    int q = blockIdx.x;
    int tid = threadIdx.x;
    int lane = tid & 63, wv = tid >> 6;        // 8 waves
    int l15 = lane & 15, lh = lane >> 4;
    const float* qbase = qry + (size_t)q * (NDIM * NXY);

    __shared__ unsigned actL[160 * 64];        // [wt][16 granules] bf16, XOR16 swizzle (40960 B)
    __shared__ unsigned bufL[128 * 64];        // phase1: qryT[128xy][16g]; phase2: qryN[64c][16g] + simacc
    __shared__ float ssqP[4 * 128];
    __shared__ float invL[128];
    __shared__ float simF[NWT];

    // ---------------- phase 1: act ----------------
    f32x4 acc[10];
#pragma unroll
    for (int m = 0; m < 10; ++m) acc[m] = (f32x4){0.f, 0.f, 0.f, 0.f};
    float ssq = 0.f;
    int sxy = tid & 127, sgrp = tid >> 7;      // staging: xy row, c-quad group
    bool valid = sxy < NXY;
    const float* col = qbase + sxy;

    for (int c0 = 0; c0 < NDIM; c0 += 64) {
        __syncthreads();
#pragma unroll
        for (int qq = 0; qq < 4; ++qq) {
            int qd = sgrp * 4 + qq;
            int c = c0 + qd * 4;
            float v0 = valid ? col[(c + 0) * NXY] : 0.f;
            float v1 = valid ? col[(c + 1) * NXY] : 0.f;
            float v2 = valid ? col[(c + 2) * NXY] : 0.f;
            float v3 = valid ? col[(c + 3) * NXY] : 0.f;
            ssq += v0 * v0 + v1 * v1 + v2 * v2 + v3 * v3;
            unsigned g = (unsigned)(qd >> 1) ^ (unsigned)(sxy & 15);
            uint2 pk; pk.x = pkbf_(v0, v1); pk.y = pkbf_(v2, v3);
            *(uint2*)&bufL[sxy * 64 + g * 4 + (qd & 1) * 2] = pk;
        }
        __syncthreads();
#pragma unroll
        for (int kk = 0; kk < 2; ++kk) {
            unsigned g = (unsigned)(kk * 4 + lh) ^ (unsigned)l15;
            s16x8 bf = *(const s16x8*)&bufL[(wv * 16 + l15) * 64 + g * 4];
            int cW = c0 + kk * 32 + lh * 8;
#pragma unroll
            for (int m = 0; m < 10; ++m) {
                s16x8 af = *(const s16x8*)&filtb[(size_t)(m * 16 + l15) * NDIM + cW];
                acc[m] = __builtin_amdgcn_mfma_f32_16x16x32_bf16(af, bf, acc[m], 0, 0, 0);
            }
        }
    }
    ssqP[sgrp * 128 + sxy] = ssq;
    __syncthreads();
    if (tid < 128) {
        float s = ssqP[tid] + ssqP[128 + tid] + ssqP[256 + tid] + ssqP[384 + tid];
        invL[tid] = (tid < NXY) ? invl2_(s) : 0.f;
    }
    __syncthreads();
    {
        int xy = wv * 16 + l15;
        float inv = invL[xy];
        unsigned xg = (unsigned)(xy >> 3);
        unsigned xo = (unsigned)(xy & 7) * 2;
#pragma unroll
        for (int m = 0; m < 10; ++m) {
#pragma unroll
            for (int r = 0; r < 4; ++r) {
                int row = m * 16 + lh * 4 + r;
                float a = sigmoidf_(acc[m][r] * inv) * inv;
                unsigned g = xg ^ (unsigned)(row & 15);
                *(ushort*)((char*)actL + (size_t)row * 256 + g * 16 + xo) = (ushort)bfr_(a);
            }
        }
    }
    float* simacc = (float*)&bufL[64 * 64];    // 8*160*2 floats, per-wave regions
    for (int i = tid; i < 8 * NWT * 2; i += 512) simacc[i] = 0.f;

    // ---------------- phase 2: pool + sim ----------------
    float dacc[5][4], sacc2[5][4];
#pragma unroll
    for (int i = 0; i < 5; ++i)
#pragma unroll
        for (int r = 0; r < 4; ++r) { dacc[i][r] = 0.f; sacc2[i][r] = 0.f; }

    int srow = tid >> 3, sseg = tid & 7;       // phase2 staging: c row, xy segment
    for (int c0 = 0; c0 < NDIM; c0 += 64) {
        __syncthreads();
        {
            const float* rp = qbase + (size_t)(c0 + srow) * NXY;
#pragma unroll
            for (int j = 0; j < 8; ++j) {
                int xy = sseg * 16 + j * 2;
                float v0 = (xy < NXY) ? rp[xy] : 0.f;
                float v1 = (xy + 1 < NXY) ? rp[xy + 1] : 0.f;
                unsigned g = (unsigned)(xy >> 3) ^ (unsigned)(srow & 15);
                bufL[srow * 64 + g * 4 + ((xy >> 1) & 3)] = pkbf_(v0, v1);
            }
        }
        __syncthreads();
#pragma unroll
        for (int i = 0; i < 5; ++i) {
            int tI = wv + 8 * i;
            int m = tI >> 2, ns = tI & 3;
            f32x4 c4 = (f32x4){0.f, 0.f, 0.f, 0.f};
#pragma unroll
            for (int kk = 0; kk < 4; ++kk) {
                unsigned g = (unsigned)(kk * 4 + lh) ^ (unsigned)l15;
                s16x8 af = *(const s16x8*)&actL[(m * 16 + l15) * 64 + g * 4];
                s16x8 bf = *(const s16x8*)&bufL[(ns * 16 + l15) * 64 + g * 4];
                c4 = __builtin_amdgcn_mfma_f32_16x16x32_bf16(af, bf, c4, 0, 0, 0);
            }
            int cb = c0 + ns * 16 + l15;
#pragma unroll
            for (int r = 0; r < 4; ++r) {
                int wt = m * 16 + lh * 4 + r;
                float p = proto[(size_t)wt * NDIM + cb];
                dacc[i][r] += c4[r] * p;
                sacc2[i][r] += c4[r] * c4[r];
            }
        }
    }
    // flush: reduce over the 16-lane column group, then per-wave LDS accumulate
#pragma unroll
    for (int i = 0; i < 5; ++i) {
#pragma unroll
        for (int r = 0; r < 4; ++r) {
            float d = dacc[i][r], s2 = sacc2[i][r];
#pragma unroll
            for (int off = 1; off < 16; off <<= 1) {
                d += __shfl_xor(d, off, 64);
                s2 += __shfl_xor(s2, off, 64);
            }
            if (l15 == 0) {
                int m = (wv + 8 * i) >> 2;
                int wt = m * 16 + lh * 4 + r;
                simacc[(wv * NWT + wt) * 2 + 0] += d;
                simacc[(wv * NWT + wt) * 2 + 1] += s2;
            }
        }
    }
    __syncthreads();
    if (tid < NWT) {
        float d = 0.f, s2 = 0.f;
#pragma unroll
        for (int w8 = 0; w8 < 8; ++w8) {
            d += simacc[(w8 * NWT + tid) * 2 + 0];
            s2 += simacc[(w8 * NWT + tid) * 2 + 1];
        }
        simF[tid] = d * invl2_(s2);
    }
    __syncthreads();
    if (tid < NWAY) {
        float lg = 0.f;
#pragma unroll
        for (int t = 0; t < NT; ++t) lg += simF[tid * NT + t] * wgt[tid * NT + t];
        out[q * NWAY + tid] = 2.0f * lg;   // / TEMP
    }
}

extern "C" void kernel_launch(void* const* d_in, const int* in_sizes, int n_in,
                              void* d_out, int out_size, void* d_ws, size_t ws_size,
                              hipStream_t stream)
{
    const float* spt  = (const float*)d_in[0];
    const float* qry  = (const float*)d_in[1];
    const float* l2v  = (const float*)d_in[2];
    const float* w1   = (const float*)d_in[3];
    const float* b1   = (const float*)d_in[4];
    const float* w2   = (const float*)d_in[5];
    const float* b2   = (const float*)d_in[6];
    const float* wb   = (const float*)d_in[7];
    const float* wq   = (const float*)d_in[8];
    const float* bq   = (const float*)d_in[9];
    const float* wk   = (const float*)d_in[10];
    const float* sat  = (const float*)d_in[11];
    const float* lamn = (const float*)d_in[12];
    const float* lamb = (const float*)d_in[13];
    const float* wt1  = (const float*)d_in[14];
    const float* bt1  = (const float*)d_in[15];
    const float* wt2  = (const float*)d_in[16];
    const float* bt2  = (const float*)d_in[17];
    const float* tb   = (const float*)d_in[18];
    const float* tl1  = (const float*)d_in[19];
    const float* tl2  = (const float*)d_in[20];

    float* ws    = (float*)d_ws;
    float* filt  = ws;                       // 160*640      = 102400
    ushort* filtb = (ushort*)(filt + 102400);// 160*640 u16  = 51200 floats
    float* wgt   = filt + 102400 + 51200;    // 160
    float* wbn   = wgt + 160;                // 2808*640     = 1797120
    float* wkn   = wbn + 1797120;            // 1797120
    float* sptn  = wkn + 1797120;            // 100*8*640    = 512000
    float* combv = sptn + 512000;            // 512000
    float* proto = combv + 512000;           // 102400
    float* outp  = (float*)d_out;

    hipLaunchKernelGGL(k_filt,    dim3(160),      dim3(256), 0, stream, l2v, w1, b1, w2, b2, filt, filtb);
    hipLaunchKernelGGL(k_wgt,     dim3(20),       dim3(256), 0, stream, l2v, wt1, bt1, wt2, bt2, tb, tl1, tl2, wgt);
    hipLaunchKernelGGL(k_rownorm, dim3(2808 * 2), dim3(128), 0, stream, wb, wk, wbn, wkn);
    hipLaunchKernelGGL(k_support, dim3(20, 5),    dim3(128), 0, stream, spt, filt, sptn);
    hipLaunchKernelGGL(k_weight,  dim3(800),      dim3(256), 0, stream, sptn, wq, bq, wkn, wbn, sat, lamn, lamb, combv);
    hipLaunchKernelGGL(k_proto,   dim3(160),      dim3(128), 0, stream, combv, proto);
    hipLaunchKernelGGL(k_query,   dim3(1000),     dim3(512), 0, stream, qry, filtb, proto, wgt, outp);
}

// Round 3
// 1089.787 us; speedup vs baseline: 2.8079x; 1.2480x over previous
//
#include <hip/hip_runtime.h>
#include <hip/hip_bf16.h>

#define NWAY 20
#define NSHOT 5
#define NT 8
#define NDIM 640
#define NSEM 300
#define NSEMH 150
#define NCLS 351
#define NXY 121
#define NWT 160   // NWAY*NT, indexed wt = w*8 + t

typedef short s16x8 __attribute__((ext_vector_type(8)));
typedef float f32x4 __attribute__((ext_vector_type(4)));
typedef float f32x4u __attribute__((ext_vector_type(4), aligned(4)));

__device__ __forceinline__ float sigmoidf_(float x) { return 1.0f / (1.0f + expf(-x)); }
__device__ __forceinline__ float lreluf_(float x) { return x >= 0.0f ? x : 0.1f * x; }
__device__ __forceinline__ float invl2_(float ss) { return 1.0f / fmaxf(sqrtf(ss), 1e-12f); }

__device__ __forceinline__ unsigned bfr_(float f) {
    unsigned b = __float_as_uint(f);
    return (b + 0x7FFFu + ((b >> 16) & 1u)) >> 16;   // RNE to bf16
}
__device__ __forceinline__ unsigned pkbf_(float a, float b) { return bfr_(a) | (bfr_(b) << 16); }

// load 8 consecutive floats (4B-aligned) -> bf16x8
__device__ __forceinline__ s16x8 cvt8_(const float* p) {
    f32x4u a = *(const f32x4u*)p;
    f32x4u b = *(const f32x4u*)(p + 4);
    union { unsigned u[4]; s16x8 v; } r;
    r.u[0] = pkbf_(a[0], a[1]); r.u[1] = pkbf_(a[2], a[3]);
    r.u[2] = pkbf_(b[0], b[1]); r.u[3] = pkbf_(b[2], b[3]);
    return r.v;
}

__device__ __forceinline__ float waveReduceSum(float v) {
#pragma unroll
    for (int off = 32; off > 0; off >>= 1) v += __shfl_down(v, off, 64);
    return v;
}

// ---------------------------------------------------------------- k_filt
__global__ __launch_bounds__(256) void k_filt(const float* __restrict__ l2v,
    const float* __restrict__ w1, const float* __restrict__ b1,
    const float* __restrict__ w2, const float* __restrict__ b2,
    ushort* __restrict__ filtb)
{
    int wt = blockIdx.x;
    int w = wt >> 3, t = wt & 7;
    int tid = threadIdx.x, lane = tid & 63, wv = tid >> 6;
    __shared__ float h_lds[NSEM];
    __shared__ float f_lds[NDIM];
    __shared__ float red[4];
    for (int j = 0; j < 75; ++j) {
        int d = wv * 75 + j;
        float acc = 0.f;
#pragma unroll
        for (int m = 0; m < 5; ++m) {
            int s = lane + 64 * m;
            if (s < NSEM) acc += l2v[w * NSEM + s] * w1[((size_t)t * NSEM + d) * NSEM + s];
        }
        acc = waveReduceSum(acc);
        if (lane == 0) h_lds[d] = lreluf_(acc + b1[t * NSEM + d]);
    }
    __syncthreads();
    for (int j = 0; j < 160; ++j) {
        int c = wv * 160 + j;
        float acc = 0.f;
#pragma unroll
        for (int m = 0; m < 5; ++m) {
            int d = lane + 64 * m;
            if (d < NSEM) acc += h_lds[d] * w2[((size_t)t * NDIM + c) * NSEM + d];
        }
        acc = waveReduceSum(acc);
        if (lane == 0) f_lds[c] = acc + b2[t * NDIM + c];
    }
    __syncthreads();
    float s = 0.f;
    for (int c = tid; c < NDIM; c += 256) s += f_lds[c] * f_lds[c];
    s = waveReduceSum(s);
    if (lane == 0) red[wv] = s;
    __syncthreads();
    float inv = invl2_(red[0] + red[1] + red[2] + red[3]);
    for (int c = tid; c < NDIM; c += 256)
        filtb[(size_t)wt * NDIM + c] = (ushort)bfr_(f_lds[c] * inv);
}

// ---------------------------------------------------------------- k_wgt
__global__ __launch_bounds__(256) void k_wgt(const float* __restrict__ l2v,
    const float* __restrict__ wt1, const float* __restrict__ bt1,
    const float* __restrict__ wt2, const float* __restrict__ bt2,
    const float* __restrict__ tb, const float* __restrict__ tl1,
    const float* __restrict__ tl2, float* __restrict__ wgt)
{
    int w = blockIdx.x;
    int tid = threadIdx.x;
    __shared__ float h2[NSEMH];
    __shared__ float wl[NT];
    __shared__ float ssum;
    if (tid < NSEMH) {
        float acc = 0.f;
        for (int s = 0; s < NSEM; ++s) acc += l2v[w * NSEM + s] * wt1[tid * NSEM + s];
        h2[tid] = lreluf_(acc + bt1[tid]);
    }
    __syncthreads();
    if (tid < NT) {
        float acc = 0.f;
        for (int d = 0; d < NSEMH; ++d) acc += h2[d] * wt2[tid * NSEMH + d];
        float wg = sigmoidf_(acc + bt2[tid]);
        wl[tid] = tl1[0] * tl1[0] * sigmoidf_(tb[tid]) + tl2[0] * tl2[0] * wg;
    }
    __syncthreads();
    if (tid == 0) { float s2 = 0.f; for (int t = 0; t < NT; ++t) s2 += wl[t]; ssum = s2; }
    __syncthreads();
    if (tid < NT) wgt[w * NT + tid] = wl[tid] / ssum;
}

// ---------------------------------------------------------------- k_cvtwq : wq fp32 -> bf16
__global__ __launch_bounds__(256) void k_cvtwq(const float* __restrict__ wq,
    unsigned* __restrict__ wqb_u)
{
    size_t i = ((size_t)blockIdx.x * 256 + threadIdx.x) * 8;
    const f32x4u a = *(const f32x4u*)(wq + i);
    const f32x4u b = *(const f32x4u*)(wq + i + 4);
    wqb_u[i / 2 + 0] = pkbf_(a[0], a[1]);
    wqb_u[i / 2 + 1] = pkbf_(a[2], a[3]);
    wqb_u[i / 2 + 2] = pkbf_(b[0], b[1]);
    wqb_u[i / 2 + 3] = pkbf_(b[2], b[3]);
}

// ---------------------------------------------------------------- k_wknorm : wkeys -> l2n bf16 [t][384pad][640]
__global__ __launch_bounds__(128) void k_wknorm(const float* __restrict__ wk,
    ushort* __restrict__ wknb)
{
    int r = blockIdx.x;                 // r = t*351 + k
    int t = r / NCLS, k = r - t * NCLS;
    const float* src = wk + (size_t)r * NDIM;
    int tid = threadIdx.x, lane = tid & 63, wv = tid >> 6;
    __shared__ float red[2];
    float v[5]; float ss = 0.f;
#pragma unroll
    for (int m = 0; m < 5; ++m) { v[m] = src[tid + 128 * m]; ss += v[m] * v[m]; }
    ss = waveReduceSum(ss);
    if (lane == 0) red[wv] = ss;
    __syncthreads();
    float inv = invl2_(red[0] + red[1]);
    ushort* dst = wknb + ((size_t)t * 384 + k) * NDIM;
#pragma unroll
    for (int m = 0; m < 5; ++m) dst[tid + 128 * m] = (ushort)bfr_(v[m] * inv);
}

// ---------------------------------------------------------------- k_wbinv : per-row inv norms of weight_base
__global__ __launch_bounds__(128) void k_wbinv(const float* __restrict__ wb,
    float* __restrict__ invb)
{
    int r = blockIdx.x;                 // r = k*8 + t
    const float* src = wb + (size_t)r * NDIM;
    int tid = threadIdx.x, lane = tid & 63, wv = tid >> 6;
    __shared__ float red[2];
    float ss = 0.f;
#pragma unroll
    for (int m = 0; m < 5; ++m) { float v = src[tid + 128 * m]; ss += v * v; }
    ss = waveReduceSum(ss);
    if (lane == 0) red[wv] = ss;
    __syncthreads();
    if (tid == 0) invb[r] = invl2_(red[0] + red[1]);
}

// ---------------------------------------------------------------- k_wbT : wbn^T bf16 [t][c 640][k 384pad]
__global__ __launch_bounds__(256) void k_wbT(const float* __restrict__ wb,
    const float* __restrict__ invb, unsigned* __restrict__ wbnT_u)
{
    int k0 = blockIdx.x * 64, c0 = blockIdx.y * 64, t = blockIdx.z;
    int tid = threadIdx.x;
    __shared__ float tile[64][65];
    __shared__ float invT[64];
    {
        int i = tid >> 2, q = tid & 3;
        int kg = min(k0 + i, NCLS - 1);
#pragma unroll
        for (int u = 0; u < 4; ++u) {
            int c = q * 16 + u * 4;
            f32x4u v = *(const f32x4u*)(wb + ((size_t)kg * NT + t) * NDIM + c0 + c);
            tile[i][c] = v[0]; tile[i][c + 1] = v[1]; tile[i][c + 2] = v[2]; tile[i][c + 3] = v[3];
        }
        if (tid < 64) {
            int kg2 = k0 + tid;
            invT[tid] = (kg2 < NCLS) ? invb[(size_t)kg2 * NT + t] : 0.f;
        }
    }
    __syncthreads();
    int cc = tid >> 2, qq = tid & 3;
    size_t rowo = (((size_t)t * NDIM + c0 + cc) * 384 + k0) / 2;
#pragma unroll
    for (int u = 0; u < 8; ++u) {
        int kl = qq * 16 + u * 2;
        float v0 = tile[kl][cc] * invT[kl];
        float v1 = tile[kl + 1][cc] * invT[kl + 1];
        wbnT_u[rowo + qq * 8 + u] = pkbf_(v0, v1);
    }
}

// ---------------------------------------------------------------- k_support2
// per (w,s) image: MFMA act (M=16pad,K=640) then MFMA pooling (K=128pad)
__global__ __launch_bounds__(512) void k_support2(const float* __restrict__ spt,
    const ushort* __restrict__ filtb, float* __restrict__ sptn,
    ushort* __restrict__ xb)
{
    int w = blockIdx.x, s = blockIdx.y;
    int n = s * NWAY + w;
    int tid = threadIdx.x, lane = tid & 63, wv = tid >> 6;     // 8 waves
    int l15 = lane & 15, lh = lane >> 4;
    const float* base = spt + (size_t)n * NDIM * NXY;

    __shared__ unsigned bufL[128 * 64];     // phase-1 qryT staging, XOR-swizzled (32 KB)
    __shared__ unsigned actL[16 * 64];      // act [16 t rows][128 xy] bf16 swizzled (4 KB)
    __shared__ float ssqP[4 * 128];
    __shared__ float invL[128];
    __shared__ float redT[8 * 8];
    __shared__ float invt[8];

    for (int i = tid; i < 16 * 64; i += 512) actL[i] = 0u;

    // ---------- phase 1: act ----------
    f32x4 acc = {0.f, 0.f, 0.f, 0.f};
    float ssq = 0.f;
    int sxy = tid & 127, sgrp = tid >> 7;
    bool valid = sxy < NXY;
    const float* col = base + sxy;
    const ushort* arow1 = filtb + (size_t)(w * NT + (l15 & 7)) * NDIM + lh * 8;

    for (int c0 = 0; c0 < NDIM; c0 += 64) {
        __syncthreads();
#pragma unroll
        for (int qq = 0; qq < 4; ++qq) {
            int qd = sgrp * 4 + qq;
            int c = c0 + qd * 4;
            float v0 = valid ? col[(c + 0) * NXY] : 0.f;
            float v1 = valid ? col[(c + 1) * NXY] : 0.f;
            float v2 = valid ? col[(c + 2) * NXY] : 0.f;
            float v3 = valid ? col[(c + 3) * NXY] : 0.f;
            ssq += v0 * v0 + v1 * v1 + v2 * v2 + v3 * v3;
            unsigned g = (unsigned)(qd >> 1) ^ (unsigned)(sxy & 15);
            uint2 pk; pk.x = pkbf_(v0, v1); pk.y = pkbf_(v2, v3);
            *(uint2*)&bufL[sxy * 64 + g * 4 + (qd & 1) * 2] = pk;
        }
        __syncthreads();
#pragma unroll
        for (int kk = 0; kk < 2; ++kk) {
            unsigned g = (unsigned)(kk * 4 + lh) ^ (unsigned)l15;
            s16x8 bf = *(const s16x8*)&bufL[(wv * 16 + l15) * 64 + g * 4];
            s16x8 af = *(const s16x8*)(arow1 + c0 + kk * 32);
            acc = __builtin_amdgcn_mfma_f32_16x16x32_bf16(af, bf, acc, 0, 0, 0);
        }
    }
    ssqP[sgrp * 128 + sxy] = ssq;
    __syncthreads();
    if (tid < 128) {
        float t4 = ssqP[tid] + ssqP[128 + tid] + ssqP[256 + tid] + ssqP[384 + tid];
        invL[tid] = (tid < NXY) ? invl2_(t4) : 0.f;
    }
    __syncthreads();
    {
        int xy = wv * 16 + l15;
        float inv = invL[xy];
#pragma unroll
        for (int r = 0; r < 4; ++r) {
            int row = lh * 4 + r;
            if (row < 8) {
                float a = sigmoidf_(acc[r] * inv) * inv;
                unsigned g = ((unsigned)(xy >> 3) ^ (unsigned)row) & 15u;
                *(ushort*)((char*)actL + (size_t)row * 256 + g * 16 + (xy & 7) * 2) = (ushort)bfr_(a);
            }
        }
    }
    __syncthreads();

    // ---------- phase 2: pooling ----------
    f32x4 acc2[5];
#pragma unroll
    for (int f = 0; f < 5; ++f) acc2[f] = (f32x4){0.f, 0.f, 0.f, 0.f};
#pragma unroll
    for (int ks = 0; ks < 4; ++ks) {
        int xyb = ks * 32 + lh * 8;
        unsigned g = ((unsigned)(ks * 4 + lh) ^ (unsigned)l15) & 15u;
        s16x8 af = *(const s16x8*)&actL[l15 * 64 + g * 4];
#pragma unroll
        for (int f = 0; f < 5; ++f) {
            int c = (wv * 5 + f) * 16 + l15;
            const float* rp = base + (size_t)c * NXY;
            s16x8 bfv;
            if (ks == 3 && lh == 3) {
                union { unsigned u[4]; s16x8 v; } r;
                r.u[0] = pkbf_(rp[120], 0.f); r.u[1] = 0u; r.u[2] = 0u; r.u[3] = 0u;
                bfv = r.v;
            } else {
                bfv = cvt8_(rp + xyb);
            }
            acc2[f] = __builtin_amdgcn_mfma_f32_16x16x32_bf16(af, bfv, acc2[f], 0, 0, 0);
        }
    }
    // ssq per t over c, rows t<8 live in lanes lh<2
    {
        float pr[4] = {0.f, 0.f, 0.f, 0.f};
#pragma unroll
        for (int f = 0; f < 5; ++f)
#pragma unroll
            for (int r = 0; r < 4; ++r) pr[r] += acc2[f][r] * acc2[f][r];
#pragma unroll
        for (int r = 0; r < 4; ++r) {
#pragma unroll
            for (int off = 1; off < 16; off <<= 1) pr[r] += __shfl_xor(pr[r], off, 64);
        }
        if (l15 == 0 && lh < 2) {
#pragma unroll
            for (int r = 0; r < 4; ++r) redT[wv * 8 + lh * 4 + r] = pr[r];
        }
    }
    __syncthreads();
    if (tid < 8) {
        float s8 = 0.f;
#pragma unroll
        for (int w8 = 0; w8 < 8; ++w8) s8 += redT[w8 * 8 + tid];
        invt[tid] = invl2_(s8);
    }
    __syncthreads();
    if (lh < 2) {
#pragma unroll
        for (int f = 0; f < 5; ++f) {
            int c = (wv * 5 + f) * 16 + l15;
#pragma unroll
            for (int r = 0; r < 4; ++r) {
                int t = lh * 4 + r;
                float val = acc2[f][r] * invt[t];
                sptn[((size_t)n * NT + t) * NDIM + c] = val;
                xb[((size_t)t * 112 + n) * NDIM + c] = (ushort)bfr_(val);
            }
        }
    }
}

// ---------------------------------------------------------------- k_qe
// per (t, mtile): QE[16 n x 640 d] = X @ wq^T + bq, then l2n rows -> qeb bf16
__global__ __launch_bounds__(256) void k_qe(const ushort* __restrict__ xb,
    const ushort* __restrict__ wqb, const float* __restrict__ bq,
    ushort* __restrict__ qeb)
{
    int t = blockIdx.x, n0 = blockIdx.y * 16;
    int tid = threadIdx.x, lane = tid & 63, wv = tid >> 6;     // 4 waves
    int l15 = lane & 15, lh = lane >> 4;
    __shared__ float red[4 * 16];
    __shared__ float invR[16];
    f32x4 acc[10];
#pragma unroll
    for (int f = 0; f < 10; ++f) acc[f] = (f32x4){0.f, 0.f, 0.f, 0.f};
    float bqv[10];
#pragma unroll
    for (int f = 0; f < 10; ++f) bqv[f] = bq[t * NDIM + (wv * 10 + f) * 16 + l15];

    const ushort* arow = xb + ((size_t)t * 112 + n0 + l15) * NDIM + lh * 8;
    for (int k0 = 0; k0 < NDIM; k0 += 32) {
        s16x8 af = *(const s16x8*)(arow + k0);
#pragma unroll
        for (int f = 0; f < 10; ++f) {
            int d = (wv * 10 + f) * 16 + l15;
            s16x8 bv = *(const s16x8*)&wqb[((size_t)t * NDIM + d) * NDIM + k0 + lh * 8];
            acc[f] = __builtin_amdgcn_mfma_f32_16x16x32_bf16(af, bv, acc[f], 0, 0, 0);
        }
    }
    {
        float pr[4] = {0.f, 0.f, 0.f, 0.f};
#pragma unroll
        for (int f = 0; f < 10; ++f)
#pragma unroll
            for (int r = 0; r < 4; ++r) { float qe = acc[f][r] + bqv[f]; pr[r] += qe * qe; }
#pragma unroll
        for (int r = 0; r < 4; ++r) {
#pragma unroll
            for (int off = 1; off < 16; off <<= 1) pr[r] += __shfl_xor(pr[r], off, 64);
        }
        if (l15 == 0) {
#pragma unroll
            for (int r = 0; r < 4; ++r) red[wv * 16 + lh * 4 + r] = pr[r];
        }
    }
    __syncthreads();
    if (tid < 16) invR[tid] = invl2_(red[tid] + red[16 + tid] + red[32 + tid] + red[48 + tid]);
    __syncthreads();
#pragma unroll
    for (int f = 0; f < 10; ++f) {
        int d = (wv * 10 + f) * 16 + l15;
#pragma unroll
        for (int r = 0; r < 4; ++r) {
            int nl = lh * 4 + r;
            float qe = (acc[f][r] + bqv[f]) * invR[nl];
            qeb[((size_t)t * 112 + n0 + nl) * NDIM + d] = (ushort)bfr_(qe);
        }
    }
}

// ---------------------------------------------------------------- k_att
// per (t, mtile): scores -> softmax -> wtb -> comb
__global__ __launch_bounds__(512) void k_att(const ushort* __restrict__ qeb,
    const ushort* __restrict__ wknb, const ushort* __restrict__ wbnT,
    unsigned* __restrict__ attb, const float* __restrict__ sptn,
    const float* __restrict__ scale_att, const float* __restrict__ lamn,
    const float* __restrict__ lamb, float* __restrict__ comb)
{
    int t = blockIdx.x, mt = blockIdx.y, n0 = mt * 16;
    int blockrow = t * 7 + mt;
    int tid = threadIdx.x, lane = tid & 63, wv = tid >> 6;     // 8 waves
    int l15 = lane & 15, lh = lane >> 4;
    __shared__ float scL[16 * 384];

    // phase 1: scores [16 n x 384 k]
    f32x4 a3[3];
#pragma unroll
    for (int f = 0; f < 3; ++f) a3[f] = (f32x4){0.f, 0.f, 0.f, 0.f};
    const ushort* arow = qeb + ((size_t)t * 112 + n0 + l15) * NDIM + lh * 8;
    for (int k0 = 0; k0 < NDIM; k0 += 32) {
        s16x8 af = *(const s16x8*)(arow + k0);
#pragma unroll
        for (int f = 0; f < 3; ++f) {
            int kk = (wv * 3 + f) * 16 + l15;
            s16x8 bv = *(const s16x8*)&wknb[((size_t)t * 384 + kk) * NDIM + k0 + lh * 8];
            a3[f] = __builtin_amdgcn_mfma_f32_16x16x32_bf16(af, bv, a3[f], 0, 0, 0);
        }
    }
    float sat = scale_att[t];
#pragma unroll
    for (int f = 0; f < 3; ++f) {
        int kk = (wv * 3 + f) * 16 + l15;
#pragma unroll
        for (int r = 0; r < 4; ++r) scL[(lh * 4 + r) * 384 + kk] = sat * a3[f][r];
    }
    __syncthreads();
    // softmax per row over 351 keys (16 rows x 32 threads)
    {
        int row = tid >> 5, li = tid & 31;
        float e[12]; float mx = -1e30f;
#pragma unroll
        for (int j = 0; j < 12; ++j) {
            int k = li + 32 * j;
            float v = (k < NCLS) ? scL[row * 384 + k] : -1e30f;
            e[j] = v; mx = fmaxf(mx, v);
        }
#pragma unroll
        for (int off = 1; off < 32; off <<= 1) mx = fmaxf(mx, __shfl_xor(mx, off, 64));
        float se = 0.f;
#pragma unroll
        for (int j = 0; j < 12; ++j) {
            int k = li + 32 * j;
            float ev = (k < NCLS) ? expf(e[j] - mx) : 0.f;
            e[j] = ev; se += ev;
        }
#pragma unroll
        for (int off = 1; off < 32; off <<= 1) se += __shfl_xor(se, off, 64);
        float is = 1.f / se;
#pragma unroll
        for (int j = 0; j < 12; ++j) scL[row * 384 + li + 32 * j] = e[j] * is;
    }
    __syncthreads();
    // pack att -> global bf16
    for (int idx = tid; idx < 3072; idx += 512) {
        int row = idx / 192, pp = idx - row * 192;
        attb[(size_t)blockrow * 3072 + idx] = pkbf_(scL[row * 384 + 2 * pp], scL[row * 384 + 2 * pp + 1]);
    }
    __syncthreads();
    // phase 2: wtb [16 n x 640 c] = att @ wbnT
    f32x4 a4[5];
#pragma unroll
    for (int f = 0; f < 5; ++f) a4[f] = (f32x4){0.f, 0.f, 0.f, 0.f};
    const ushort* attp = (const ushort*)attb;
    const ushort* arow2 = attp + ((size_t)blockrow * 16 + l15) * 384 + lh * 8;
    for (int k0 = 0; k0 < 384; k0 += 32) {
        s16x8 af = *(const s16x8*)(arow2 + k0);
#pragma unroll
        for (int f = 0; f < 5; ++f) {
            int c = (wv * 5 + f) * 16 + l15;
            s16x8 bv = *(const s16x8*)&wbnT[((size_t)t * NDIM + c) * 384 + k0 + lh * 8];
            a4[f] = __builtin_amdgcn_mfma_f32_16x16x32_bf16(af, bv, a4[f], 0, 0, 0);
        }
    }
    float ln2 = lamn[t] * lamn[t], lb2 = lamb[t] * lamb[t];
#pragma unroll
    for (int f = 0; f < 5; ++f) {
        int c = (wv * 5 + f) * 16 + l15;
#pragma unroll
        for (int r = 0; r < 4; ++r) {
            int ng = n0 + lh * 4 + r;
            if (ng < 100) {
                size_t o = ((size_t)ng * NT + t) * NDIM + c;
                comb[o] = ln2 * sptn[o] + lb2 * a4[f][r];
            }
        }
    }
}

// ---------------------------------------------------------------- k_proto
__global__ __launch_bounds__(128) void k_proto(const float* __restrict__ comb,
    float* __restrict__ proto)
{
    int wt = blockIdx.x;
    int w = wt >> 3, t = wt & 7;
    int tid = threadIdx.x, lane = tid & 63, wv = tid >> 6;
    __shared__ float red[2];
    float mv[5]; float ss = 0.f;
#pragma unroll
    for (int m = 0; m < 5; ++m) {
        int c = tid + 128 * m;
        float a = 0.f;
#pragma unroll
        for (int s = 0; s < NSHOT; ++s)
            a += comb[(((size_t)(s * NWAY + w)) * NT + t) * NDIM + c];
        a *= 0.2f;
        mv[m] = a; ss += a * a;
    }
    ss = waveReduceSum(ss);
    if (lane == 0) red[wv] = ss;
    __syncthreads();
    float inv = invl2_(red[0] + red[1]);
#pragma unroll
    for (int m = 0; m < 5; ++m) proto[(size_t)wt * NDIM + tid + 128 * m] = mv[m] * inv;
}

// ---------------------------------------------------------------- k_query
__global__ __launch_bounds__(512, 1) void k_query(const float* __restrict__ qry,
    const ushort* __restrict__ filtb, const float* __restrict__ proto,
    const float* __restrict__ wgt, float* __restrict__ out)
{
    int q = blockIdx.x;
    int tid = threadIdx.x;
    int lane = tid & 63, wv = tid >> 6;        // 8 waves
    int l15 = lane & 15, lh = lane >> 4;
    const float* qbase = qry + (size_t)q * (NDIM * NXY);

    __shared__ unsigned actL[160 * 64];        // [wt][granules] bf16, XOR16 swizzle (40960 B)
    __shared__ unsigned bufL[128 * 64];        // phase-1 qryT staging; tail holds simacc
    __shared__ float ssqP[4 * 128];
    __shared__ float invL[128];
    __shared__ float simF[NWT];

    // ---------------- phase 1: act ----------------
    f32x4 acc[10];
#pragma unroll
    for (int m = 0; m < 10; ++m) acc[m] = (f32x4){0.f, 0.f, 0.f, 0.f};
    float ssq = 0.f;
    int sxy = tid & 127, sgrp = tid >> 7;
    bool valid = sxy < NXY;
    const float* col = qbase + sxy;

    for (int c0 = 0; c0 < NDIM; c0 += 64) {
        __syncthreads();
#pragma unroll
        for (int qq = 0; qq < 4; ++qq) {
            int qd = sgrp * 4 + qq;
            int c = c0 + qd * 4;
            float v0 = valid ? col[(c + 0) * NXY] : 0.f;
            float v1 = valid ? col[(c + 1) * NXY] : 0.f;
            float v2 = valid ? col[(c + 2) * NXY] : 0.f;
            float v3 = valid ? col[(c + 3) * NXY] : 0.f;
            ssq += v0 * v0 + v1 * v1 + v2 * v2 + v3 * v3;
            unsigned g = (unsigned)(qd >> 1) ^ (unsigned)(sxy & 15);
            uint2 pk; pk.x = pkbf_(v0, v1); pk.y = pkbf_(v2, v3);
            *(uint2*)&bufL[sxy * 64 + g * 4 + (qd & 1) * 2] = pk;
        }
        __syncthreads();
#pragma unroll
        for (int kk = 0; kk < 2; ++kk) {
            unsigned g = (unsigned)(kk * 4 + lh) ^ (unsigned)l15;
            s16x8 bf = *(const s16x8*)&bufL[(wv * 16 + l15) * 64 + g * 4];
            int cW = c0 + kk * 32 + lh * 8;
#pragma unroll
            for (int m = 0; m < 10; ++m) {
                s16x8 af = *(const s16x8*)&filtb[(size_t)(m * 16 + l15) * NDIM + cW];
                acc[m] = __builtin_amdgcn_mfma_f32_16x16x32_bf16(af, bf, acc[m], 0, 0, 0);
            }
        }
    }
    ssqP[sgrp * 128 + sxy] = ssq;
    __syncthreads();
    if (tid < 128) {
        float s = ssqP[tid] + ssqP[128 + tid] + ssqP[256 + tid] + ssqP[384 + tid];
        invL[tid] = (tid < NXY) ? invl2_(s) : 0.f;
    }
    __syncthreads();
    {
        int xy = wv * 16 + l15;
        float inv = invL[xy];
        unsigned xg = (unsigned)(xy >> 3);
        unsigned xo = (unsigned)(xy & 7) * 2;
#pragma unroll
        for (int m = 0; m < 10; ++m) {
#pragma unroll
            for (int r = 0; r < 4; ++r) {
                int row = m * 16 + lh * 4 + r;
                float a = sigmoidf_(acc[m][r] * inv) * inv;
                unsigned g = xg ^ (unsigned)(row & 15);
                *(ushort*)((char*)actL + (size_t)row * 256 + g * 16 + xo) = (ushort)bfr_(a);
            }
        }
    }
    float* simacc = (float*)&bufL[64 * 64];    // 8*160*2 floats
    for (int i = tid; i < 8 * NWT * 2; i += 512) simacc[i] = 0.f;
    __syncthreads();

    // ---------------- phase 2: pool + sim (B direct from global) ----------------
    float dacc[5][4], sacc2[5][4];
#pragma unroll
    for (int i = 0; i < 5; ++i)
#pragma unroll
        for (int j = 0; j < 4; ++j) { dacc[i][j] = 0.f; sacc2[i][j] = 0.f; }

    int ns = wv & 3, a_ = wv >> 2;
    for (int c0 = 0; c0 < NDIM; c0 += 64) {
        int cb = c0 + ns * 16 + l15;
        const float* rp = qbase + (size_t)cb * NXY;
        s16x8 bfv[4];
#pragma unroll
        for (int kk = 0; kk < 4; ++kk) {
            int xyb = kk * 32 + lh * 8;
            if (kk == 3 && lh == 3) {
                union { unsigned u[4]; s16x8 v; } r;
                r.u[0] = pkbf_(rp[120], 0.f); r.u[1] = 0u; r.u[2] = 0u; r.u[3] = 0u;
                bfv[kk] = r.v;
            } else {
                bfv[kk] = cvt8_(rp + xyb);
            }
        }
#pragma unroll
        for (int i = 0; i < 5; ++i) {
            int m = a_ + 2 * i;
            f32x4 c4 = (f32x4){0.f, 0.f, 0.f, 0.f};
#pragma unroll
            for (int kk = 0; kk < 4; ++kk) {
                unsigned g = (unsigned)(kk * 4 + lh) ^ (unsigned)l15;
                s16x8 af = *(const s16x8*)&actL[(m * 16 + l15) * 64 + g * 4];
                c4 = __builtin_amdgcn_mfma_f32_16x16x32_bf16(af, bfv[kk], c4, 0, 0, 0);
            }
#pragma unroll
            for (int r = 0; r < 4; ++r) {
                float p = proto[(size_t)(m * 16 + lh * 4 + r) * NDIM + cb];
                dacc[i][r] += c4[r] * p;
                sacc2[i][r] += c4[r] * c4[r];
            }
        }
    }
    // flush
#pragma unroll
    for (int i = 0; i < 5; ++i) {
#pragma unroll
        for (int r = 0; r < 4; ++r) {
            float d = dacc[i][r], s2 = sacc2[i][r];
#pragma unroll
            for (int off = 1; off < 16; off <<= 1) {
                d += __shfl_xor(d, off, 64);
                s2 += __shfl_xor(s2, off, 64);
            }
            if (l15 == 0) {
                int m = (wv + 8 * i) >> 2;
                int wt = m * 16 + lh * 4 + r;
                simacc[(wv * NWT + wt) * 2 + 0] += d;
                simacc[(wv * NWT + wt) * 2 + 1] += s2;
            }
        }
    }
    __syncthreads();
    if (tid < NWT) {
        float d = 0.f, s2 = 0.f;
#pragma unroll
        for (int w8 = 0; w8 < 8; ++w8) {
            d += simacc[(w8 * NWT + tid) * 2 + 0];
            s2 += simacc[(w8 * NWT + tid) * 2 + 1];
        }
        simF[tid] = d * invl2_(s2);
    }
    __syncthreads();
    if (tid < NWAY) {
        float lg = 0.f;
#pragma unroll
        for (int t = 0; t < NT; ++t) lg += simF[tid * NT + t] * wgt[tid * NT + t];
        out[q * NWAY + tid] = 2.0f * lg;   // / TEMP
    }
}

extern "C" void kernel_launch(void* const* d_in, const int* in_sizes, int n_in,
                              void* d_out, int out_size, void* d_ws, size_t ws_size,
                              hipStream_t stream)
{
    const float* spt  = (const float*)d_in[0];
    const float* qry  = (const float*)d_in[1];
    const float* l2v  = (const float*)d_in[2];
    const float* w1   = (const float*)d_in[3];
    const float* b1   = (const float*)d_in[4];
    const float* w2   = (const float*)d_in[5];
    const float* b2   = (const float*)d_in[6];
    const float* wb   = (const float*)d_in[7];
    const float* wq   = (const float*)d_in[8];
    const float* bq   = (const float*)d_in[9];
    const float* wk   = (const float*)d_in[10];
    const float* sat  = (const float*)d_in[11];
    const float* lamn = (const float*)d_in[12];
    const float* lamb = (const float*)d_in[13];
    const float* wt1  = (const float*)d_in[14];
    const float* bt1  = (const float*)d_in[15];
    const float* wt2  = (const float*)d_in[16];
    const float* bt2  = (const float*)d_in[17];
    const float* tb   = (const float*)d_in[18];
    const float* tl1  = (const float*)d_in[19];
    const float* tl2  = (const float*)d_in[20];

    float* ws = (float*)d_ws;
    // layout (float slots)
    ushort*  filtb  = (ushort*)ws;                       // 160*640 bf16      = 51200 f
    float*   wgt    = ws + 51200;                        // 160
    ushort*  wqb    = (ushort*)(ws + 51360);             // 8*640*640 bf16    = 1638400 f
    ushort*  wknb   = (ushort*)(ws + 51360 + 1638400);   // 8*384*640 bf16    = 983040 f
    ushort*  wbnT   = (ushort*)(ws + 2672800);           // 8*640*384 bf16    = 983040 f
    float*   invb   = ws + 3655840;                      // 2816
    ushort*  xb     = (ushort*)(ws + 3658656);           // 8*112*640 bf16    = 286720 f
    ushort*  qeb    = (ushort*)(ws + 3945376);           // 8*112*640 bf16    = 286720 f
    unsigned* attb  = (unsigned*)(ws + 4232096);         // 56*3072 uints     = 172032 f
    float*   sptn   = ws + 4404128;                      // 100*8*640         = 512000
    float*   combv  = ws + 4916128;                      // 512000
    float*   proto  = ws + 5428128;                      // 160*640           = 102400
    float*   outp   = (float*)d_out;                     // total 5530528 f

    hipLaunchKernelGGL(k_filt,     dim3(160),        dim3(256), 0, stream, l2v, w1, b1, w2, b2, filtb);
    hipLaunchKernelGGL(k_wgt,      dim3(20),         dim3(256), 0, stream, l2v, wt1, bt1, wt2, bt2, tb, tl1, tl2, wgt);
    hipLaunchKernelGGL(k_cvtwq,    dim3(1600),       dim3(256), 0, stream, wq, (unsigned*)wqb);
    hipLaunchKernelGGL(k_wknorm,   dim3(2808),       dim3(128), 0, stream, wk, wknb);
    hipLaunchKernelGGL(k_wbinv,    dim3(2808),       dim3(128), 0, stream, wb, invb);
    hipLaunchKernelGGL(k_wbT,      dim3(6, 10, 8),   dim3(256), 0, stream, wb, invb, (unsigned*)wbnT);
    hipLaunchKernelGGL(k_support2, dim3(20, 5),      dim3(512), 0, stream, spt, filtb, sptn, xb);
    hipLaunchKernelGGL(k_qe,       dim3(8, 7),       dim3(256), 0, stream, xb, wqb, bq, qeb);
    hipLaunchKernelGGL(k_att,      dim3(8, 7),       dim3(512), 0, stream, qeb, wknb, wbnT, attb, sptn, sat, lamn, lamb, combv);
    hipLaunchKernelGGL(k_proto,    dim3(160),        dim3(128), 0, stream, combv, proto);
    hipLaunchKernelGGL(k_query,    dim3(1000),       dim3(512), 0, stream, qry, filtb, proto, wgt, outp);
}

// Round 4
// 983.963 us; speedup vs baseline: 3.1099x; 1.1075x over previous
//
#include <hip/hip_runtime.h>
#include <hip/hip_bf16.h>

#define NWAY 20
#define NSHOT 5
#define NT 8
#define NDIM 640
#define NSEM 300
#define NSEMH 150
#define NCLS 351
#define NXY 121
#define NWT 160   // NWAY*NT, indexed wt = w*8 + t

typedef short s16x8 __attribute__((ext_vector_type(8)));
typedef float f32x4 __attribute__((ext_vector_type(4)));
typedef float f32x4u __attribute__((ext_vector_type(4), aligned(4)));

__device__ __forceinline__ float sigmoidf_(float x) { return 1.0f / (1.0f + expf(-x)); }
__device__ __forceinline__ float lreluf_(float x) { return x >= 0.0f ? x : 0.1f * x; }
__device__ __forceinline__ float invl2_(float ss) { return 1.0f / fmaxf(sqrtf(ss), 1e-12f); }

__device__ __forceinline__ unsigned bfr_(float f) {
    unsigned b = __float_as_uint(f);
    return (b + 0x7FFFu + ((b >> 16) & 1u)) >> 16;   // RNE to bf16
}
__device__ __forceinline__ unsigned pkbf_(float a, float b) { return bfr_(a) | (bfr_(b) << 16); }

// load 8 consecutive floats (4B-aligned) -> bf16x8
__device__ __forceinline__ s16x8 cvt8_(const float* p) {
    f32x4u a = *(const f32x4u*)p;
    f32x4u b = *(const f32x4u*)(p + 4);
    union { unsigned u[4]; s16x8 v; } r;
    r.u[0] = pkbf_(a[0], a[1]); r.u[1] = pkbf_(a[2], a[3]);
    r.u[2] = pkbf_(b[0], b[1]); r.u[3] = pkbf_(b[2], b[3]);
    return r.v;
}

__device__ __forceinline__ float waveReduceSum(float v) {
#pragma unroll
    for (int off = 32; off > 0; off >>= 1) v += __shfl_down(v, off, 64);
    return v;
}

// ---------------------------------------------------------------- k_filt
__global__ __launch_bounds__(256) void k_filt(const float* __restrict__ l2v,
    const float* __restrict__ w1, const float* __restrict__ b1,
    const float* __restrict__ w2, const float* __restrict__ b2,
    ushort* __restrict__ filtb)
{
    int wt = blockIdx.x;
    int w = wt >> 3, t = wt & 7;
    int tid = threadIdx.x, lane = tid & 63, wv = tid >> 6;
    __shared__ float h_lds[NSEM];
    __shared__ float f_lds[NDIM];
    __shared__ float red[4];
    for (int j = 0; j < 75; ++j) {
        int d = wv * 75 + j;
        float acc = 0.f;
#pragma unroll
        for (int m = 0; m < 5; ++m) {
            int s = lane + 64 * m;
            if (s < NSEM) acc += l2v[w * NSEM + s] * w1[((size_t)t * NSEM + d) * NSEM + s];
        }
        acc = waveReduceSum(acc);
        if (lane == 0) h_lds[d] = lreluf_(acc + b1[t * NSEM + d]);
    }
    __syncthreads();
    for (int j = 0; j < 160; ++j) {
        int c = wv * 160 + j;
        float acc = 0.f;
#pragma unroll
        for (int m = 0; m < 5; ++m) {
            int d = lane + 64 * m;
            if (d < NSEM) acc += h_lds[d] * w2[((size_t)t * NDIM + c) * NSEM + d];
        }
        acc = waveReduceSum(acc);
        if (lane == 0) f_lds[c] = acc + b2[t * NDIM + c];
    }
    __syncthreads();
    float s = 0.f;
    for (int c = tid; c < NDIM; c += 256) s += f_lds[c] * f_lds[c];
    s = waveReduceSum(s);
    if (lane == 0) red[wv] = s;
    __syncthreads();
    float inv = invl2_(red[0] + red[1] + red[2] + red[3]);
    for (int c = tid; c < NDIM; c += 256)
        filtb[(size_t)wt * NDIM + c] = (ushort)bfr_(f_lds[c] * inv);
}

// ---------------------------------------------------------------- k_wgt
__global__ __launch_bounds__(256) void k_wgt(const float* __restrict__ l2v,
    const float* __restrict__ wt1, const float* __restrict__ bt1,
    const float* __restrict__ wt2, const float* __restrict__ bt2,
    const float* __restrict__ tb, const float* __restrict__ tl1,
    const float* __restrict__ tl2, float* __restrict__ wgt)
{
    int w = blockIdx.x;
    int tid = threadIdx.x;
    __shared__ float h2[NSEMH];
    __shared__ float wl[NT];
    __shared__ float ssum;
    if (tid < NSEMH) {
        float acc = 0.f;
        for (int s = 0; s < NSEM; ++s) acc += l2v[w * NSEM + s] * wt1[tid * NSEM + s];
        h2[tid] = lreluf_(acc + bt1[tid]);
    }
    __syncthreads();
    if (tid < NT) {
        float acc = 0.f;
        for (int d = 0; d < NSEMH; ++d) acc += h2[d] * wt2[tid * NSEMH + d];
        float wg = sigmoidf_(acc + bt2[tid]);
        wl[tid] = tl1[0] * tl1[0] * sigmoidf_(tb[tid]) + tl2[0] * tl2[0] * wg;
    }
    __syncthreads();
    if (tid == 0) { float s2 = 0.f; for (int t = 0; t < NT; ++t) s2 += wl[t]; ssum = s2; }
    __syncthreads();
    if (tid < NT) wgt[w * NT + tid] = wl[tid] / ssum;
}

// ---------------------------------------------------------------- k_cvtwq : wq fp32 -> bf16
__global__ __launch_bounds__(256) void k_cvtwq(const float* __restrict__ wq,
    unsigned* __restrict__ wqb_u)
{
    size_t i = ((size_t)blockIdx.x * 256 + threadIdx.x) * 8;
    const f32x4u a = *(const f32x4u*)(wq + i);
    const f32x4u b = *(const f32x4u*)(wq + i + 4);
    wqb_u[i / 2 + 0] = pkbf_(a[0], a[1]);
    wqb_u[i / 2 + 1] = pkbf_(a[2], a[3]);
    wqb_u[i / 2 + 2] = pkbf_(b[0], b[1]);
    wqb_u[i / 2 + 3] = pkbf_(b[2], b[3]);
}

// ---------------------------------------------------------------- k_wknorm : wkeys -> l2n bf16 [t][384pad][640]
__global__ __launch_bounds__(128) void k_wknorm(const float* __restrict__ wk,
    ushort* __restrict__ wknb)
{
    int r = blockIdx.x;                 // r = t*351 + k
    int t = r / NCLS, k = r - t * NCLS;
    const float* src = wk + (size_t)r * NDIM;
    int tid = threadIdx.x, lane = tid & 63, wv = tid >> 6;
    __shared__ float red[2];
    float v[5]; float ss = 0.f;
#pragma unroll
    for (int m = 0; m < 5; ++m) { v[m] = src[tid + 128 * m]; ss += v[m] * v[m]; }
    ss = waveReduceSum(ss);
    if (lane == 0) red[wv] = ss;
    __syncthreads();
    float inv = invl2_(red[0] + red[1]);
    ushort* dst = wknb + ((size_t)t * 384 + k) * NDIM;
#pragma unroll
    for (int m = 0; m < 5; ++m) dst[tid + 128 * m] = (ushort)bfr_(v[m] * inv);
}

// ---------------------------------------------------------------- k_wbinv : per-row inv norms of weight_base
__global__ __launch_bounds__(128) void k_wbinv(const float* __restrict__ wb,
    float* __restrict__ invb)
{
    int r = blockIdx.x;                 // r = k*8 + t
    const float* src = wb + (size_t)r * NDIM;
    int tid = threadIdx.x, lane = tid & 63, wv = tid >> 6;
    __shared__ float red[2];
    float ss = 0.f;
#pragma unroll
    for (int m = 0; m < 5; ++m) { float v = src[tid + 128 * m]; ss += v * v; }
    ss = waveReduceSum(ss);
    if (lane == 0) red[wv] = ss;
    __syncthreads();
    if (tid == 0) invb[r] = invl2_(red[0] + red[1]);
}

// ---------------------------------------------------------------- k_wbT : wbn^T bf16 [t][c 640][k 384pad]
__global__ __launch_bounds__(256) void k_wbT(const float* __restrict__ wb,
    const float* __restrict__ invb, unsigned* __restrict__ wbnT_u)
{
    int k0 = blockIdx.x * 64, c0 = blockIdx.y * 64, t = blockIdx.z;
    int tid = threadIdx.x;
    __shared__ float tile[64][65];
    __shared__ float invT[64];
    {
        int i = tid >> 2, q = tid & 3;
        int kg = min(k0 + i, NCLS - 1);
#pragma unroll
        for (int u = 0; u < 4; ++u) {
            int c = q * 16 + u * 4;
            f32x4u v = *(const f32x4u*)(wb + ((size_t)kg * NT + t) * NDIM + c0 + c);
            tile[i][c] = v[0]; tile[i][c + 1] = v[1]; tile[i][c + 2] = v[2]; tile[i][c + 3] = v[3];
        }
        if (tid < 64) {
            int kg2 = k0 + tid;
            invT[tid] = (kg2 < NCLS) ? invb[(size_t)kg2 * NT + t] : 0.f;
        }
    }
    __syncthreads();
    int cc = tid >> 2, qq = tid & 3;
    size_t rowo = (((size_t)t * NDIM + c0 + cc) * 384 + k0) / 2;
#pragma unroll
    for (int u = 0; u < 8; ++u) {
        int kl = qq * 16 + u * 2;
        float v0 = tile[kl][cc] * invT[kl];
        float v1 = tile[kl + 1][cc] * invT[kl + 1];
        wbnT_u[rowo + qq * 8 + u] = pkbf_(v0, v1);
    }
}

// ---------------------------------------------------------------- k_support2
// per (w,s) image: barrier-free MFMA act (rows 0..7), then MFMA pooling (K=128pad)
__global__ __launch_bounds__(512) void k_support2(const float* __restrict__ spt,
    const ushort* __restrict__ filtb, float* __restrict__ sptn,
    ushort* __restrict__ xb)
{
    int w = blockIdx.x, s = blockIdx.y;
    int n = s * NWAY + w;
    int tid = threadIdx.x, lane = tid & 63, wv = tid >> 6;     // 8 waves
    int l15 = lane & 15, lh = lane >> 4;
    const float* base = spt + (size_t)n * NDIM * NXY;

    __shared__ unsigned actL[16 * 64];      // act [16 t rows][128 xy] bf16 swizzled (4 KB)
    __shared__ float redT[8 * 8];
    __shared__ float invt[8];

    for (int i = tid; i < 16 * 64; i += 512) actL[i] = 0u;

    // ---------- phase 1: act (direct global B-fragments, no barriers) ----------
    int xy = wv * 16 + l15;
    const float* colb = base + (xy < NXY ? xy : 0);
    const ushort* arow1 = filtb + (size_t)(w * NT + (l15 & 7)) * NDIM + lh * 8;
    f32x4 acc = {0.f, 0.f, 0.f, 0.f};
    float ssq = 0.f;
    for (int c0 = 0; c0 < NDIM; c0 += 32) {
        float v[8];
#pragma unroll
        for (int j = 0; j < 8; ++j) {
            v[j] = colb[(size_t)(c0 + lh * 8 + j) * NXY];
            ssq += v[j] * v[j];
        }
        union { unsigned u[4]; s16x8 x; } bf;
#pragma unroll
        for (int p = 0; p < 4; ++p) bf.u[p] = pkbf_(v[2 * p], v[2 * p + 1]);
        s16x8 af = *(const s16x8*)(arow1 + c0);
        acc = __builtin_amdgcn_mfma_f32_16x16x32_bf16(af, bf.x, acc, 0, 0, 0);
    }
    ssq += __shfl_xor(ssq, 16, 64);
    ssq += __shfl_xor(ssq, 32, 64);
    float inv = (xy < NXY) ? invl2_(ssq) : 0.f;
    __syncthreads();   // actL zero-init complete
#pragma unroll
    for (int r = 0; r < 4; ++r) {
        int row = lh * 4 + r;
        if (row < 8) {
            float a = sigmoidf_(acc[r] * inv) * inv;
            unsigned g = ((unsigned)(xy >> 3) ^ (unsigned)row) & 15u;
            *(ushort*)((char*)actL + (size_t)row * 256 + g * 16 + (xy & 7) * 2) = (ushort)bfr_(a);
        }
    }
    __syncthreads();

    // ---------- phase 2: pooling ----------
    f32x4 acc2[5];
#pragma unroll
    for (int f = 0; f < 5; ++f) acc2[f] = (f32x4){0.f, 0.f, 0.f, 0.f};
#pragma unroll
    for (int ks = 0; ks < 4; ++ks) {
        int xyb = ks * 32 + lh * 8;
        unsigned g = ((unsigned)(ks * 4 + lh) ^ (unsigned)l15) & 15u;
        s16x8 af = *(const s16x8*)&actL[l15 * 64 + g * 4];
#pragma unroll
        for (int f = 0; f < 5; ++f) {
            int c = (wv * 5 + f) * 16 + l15;
            const float* rp = base + (size_t)c * NXY;
            s16x8 bfv;
            if (ks == 3 && lh == 3) {
                union { unsigned u[4]; s16x8 v; } r;
                r.u[0] = pkbf_(rp[120], 0.f); r.u[1] = 0u; r.u[2] = 0u; r.u[3] = 0u;
                bfv = r.v;
            } else {
                bfv = cvt8_(rp + xyb);
            }
            acc2[f] = __builtin_amdgcn_mfma_f32_16x16x32_bf16(af, bfv, acc2[f], 0, 0, 0);
        }
    }
    {
        float pr[4] = {0.f, 0.f, 0.f, 0.f};
#pragma unroll
        for (int f = 0; f < 5; ++f)
#pragma unroll
            for (int r = 0; r < 4; ++r) pr[r] += acc2[f][r] * acc2[f][r];
#pragma unroll
        for (int r = 0; r < 4; ++r) {
#pragma unroll
            for (int off = 1; off < 16; off <<= 1) pr[r] += __shfl_xor(pr[r], off, 64);
        }
        if (l15 == 0 && lh < 2) {
#pragma unroll
            for (int r = 0; r < 4; ++r) redT[wv * 8 + lh * 4 + r] = pr[r];
        }
    }
    __syncthreads();
    if (tid < 8) {
        float s8 = 0.f;
#pragma unroll
        for (int w8 = 0; w8 < 8; ++w8) s8 += redT[w8 * 8 + tid];
        invt[tid] = invl2_(s8);
    }
    __syncthreads();
    if (lh < 2) {
#pragma unroll
        for (int f = 0; f < 5; ++f) {
            int c = (wv * 5 + f) * 16 + l15;
#pragma unroll
            for (int r = 0; r < 4; ++r) {
                int t = lh * 4 + r;
                float val = acc2[f][r] * invt[t];
                sptn[((size_t)n * NT + t) * NDIM + c] = val;
                xb[((size_t)t * 112 + n) * NDIM + c] = (ushort)bfr_(val);
            }
        }
    }
}

// ---------------------------------------------------------------- k_qe
__global__ __launch_bounds__(256) void k_qe(const ushort* __restrict__ xb,
    const ushort* __restrict__ wqb, const float* __restrict__ bq,
    ushort* __restrict__ qeb)
{
    int t = blockIdx.x, n0 = blockIdx.y * 16;
    int tid = threadIdx.x, lane = tid & 63, wv = tid >> 6;     // 4 waves
    int l15 = lane & 15, lh = lane >> 4;
    __shared__ float red[4 * 16];
    __shared__ float invR[16];
    f32x4 acc[10];
#pragma unroll
    for (int f = 0; f < 10; ++f) acc[f] = (f32x4){0.f, 0.f, 0.f, 0.f};
    float bqv[10];
#pragma unroll
    for (int f = 0; f < 10; ++f) bqv[f] = bq[t * NDIM + (wv * 10 + f) * 16 + l15];

    const ushort* arow = xb + ((size_t)t * 112 + n0 + l15) * NDIM + lh * 8;
    for (int k0 = 0; k0 < NDIM; k0 += 32) {
        s16x8 af = *(const s16x8*)(arow + k0);
#pragma unroll
        for (int f = 0; f < 10; ++f) {
            int d = (wv * 10 + f) * 16 + l15;
            s16x8 bv = *(const s16x8*)&wqb[((size_t)t * NDIM + d) * NDIM + k0 + lh * 8];
            acc[f] = __builtin_amdgcn_mfma_f32_16x16x32_bf16(af, bv, acc[f], 0, 0, 0);
        }
    }
    {
        float pr[4] = {0.f, 0.f, 0.f, 0.f};
#pragma unroll
        for (int f = 0; f < 10; ++f)
#pragma unroll
            for (int r = 0; r < 4; ++r) { float qe = acc[f][r] + bqv[f]; pr[r] += qe * qe; }
#pragma unroll
        for (int r = 0; r < 4; ++r) {
#pragma unroll
            for (int off = 1; off < 16; off <<= 1) pr[r] += __shfl_xor(pr[r], off, 64);
        }
        if (l15 == 0) {
#pragma unroll
            for (int r = 0; r < 4; ++r) red[wv * 16 + lh * 4 + r] = pr[r];
        }
    }
    __syncthreads();
    if (tid < 16) invR[tid] = invl2_(red[tid] + red[16 + tid] + red[32 + tid] + red[48 + tid]);
    __syncthreads();
#pragma unroll
    for (int f = 0; f < 10; ++f) {
        int d = (wv * 10 + f) * 16 + l15;
#pragma unroll
        for (int r = 0; r < 4; ++r) {
            int nl = lh * 4 + r;
            float qe = (acc[f][r] + bqv[f]) * invR[nl];
            qeb[((size_t)t * 112 + n0 + nl) * NDIM + d] = (ushort)bfr_(qe);
        }
    }
}

// ---------------------------------------------------------------- k_att
__global__ __launch_bounds__(512) void k_att(const ushort* __restrict__ qeb,
    const ushort* __restrict__ wknb, const ushort* __restrict__ wbnT,
    unsigned* __restrict__ attb, const float* __restrict__ sptn,
    const float* __restrict__ scale_att, const float* __restrict__ lamn,
    const float* __restrict__ lamb, float* __restrict__ comb)
{
    int t = blockIdx.x, mt = blockIdx.y, n0 = mt * 16;
    int blockrow = t * 7 + mt;
    int tid = threadIdx.x, lane = tid & 63, wv = tid >> 6;     // 8 waves
    int l15 = lane & 15, lh = lane >> 4;
    __shared__ float scL[16 * 384];

    f32x4 a3[3];
#pragma unroll
    for (int f = 0; f < 3; ++f) a3[f] = (f32x4){0.f, 0.f, 0.f, 0.f};
    const ushort* arow = qeb + ((size_t)t * 112 + n0 + l15) * NDIM + lh * 8;
    for (int k0 = 0; k0 < NDIM; k0 += 32) {
        s16x8 af = *(const s16x8*)(arow + k0);
#pragma unroll
        for (int f = 0; f < 3; ++f) {
            int kk = (wv * 3 + f) * 16 + l15;
            s16x8 bv = *(const s16x8*)&wknb[((size_t)t * 384 + kk) * NDIM + k0 + lh * 8];
            a3[f] = __builtin_amdgcn_mfma_f32_16x16x32_bf16(af, bv, a3[f], 0, 0, 0);
        }
    }
    float sat = scale_att[t];
#pragma unroll
    for (int f = 0; f < 3; ++f) {
        int kk = (wv * 3 + f) * 16 + l15;
#pragma unroll
        for (int r = 0; r < 4; ++r) scL[(lh * 4 + r) * 384 + kk] = sat * a3[f][r];
    }
    __syncthreads();
    {
        int row = tid >> 5, li = tid & 31;
        float e[12]; float mx = -1e30f;
#pragma unroll
        for (int j = 0; j < 12; ++j) {
            int k = li + 32 * j;
            float v = (k < NCLS) ? scL[row * 384 + k] : -1e30f;
            e[j] = v; mx = fmaxf(mx, v);
        }
#pragma unroll
        for (int off = 1; off < 32; off <<= 1) mx = fmaxf(mx, __shfl_xor(mx, off, 64));
        float se = 0.f;
#pragma unroll
        for (int j = 0; j < 12; ++j) {
            int k = li + 32 * j;
            float ev = (k < NCLS) ? expf(e[j] - mx) : 0.f;
            e[j] = ev; se += ev;
        }
#pragma unroll
        for (int off = 1; off < 32; off <<= 1) se += __shfl_xor(se, off, 64);
        float is = 1.f / se;
#pragma unroll
        for (int j = 0; j < 12; ++j) scL[row * 384 + li + 32 * j] = e[j] * is;
    }
    __syncthreads();
    for (int idx = tid; idx < 3072; idx += 512) {
        int row = idx / 192, pp = idx - row * 192;
        attb[(size_t)blockrow * 3072 + idx] = pkbf_(scL[row * 384 + 2 * pp], scL[row * 384 + 2 * pp + 1]);
    }
    __syncthreads();
    f32x4 a4[5];
#pragma unroll
    for (int f = 0; f < 5; ++f) a4[f] = (f32x4){0.f, 0.f, 0.f, 0.f};
    const ushort* attp = (const ushort*)attb;
    const ushort* arow2 = attp + ((size_t)blockrow * 16 + l15) * 384 + lh * 8;
    for (int k0 = 0; k0 < 384; k0 += 32) {
        s16x8 af = *(const s16x8*)(arow2 + k0);
#pragma unroll
        for (int f = 0; f < 5; ++f) {
            int c = (wv * 5 + f) * 16 + l15;
            s16x8 bv = *(const s16x8*)&wbnT[((size_t)t * NDIM + c) * 384 + k0 + lh * 8];
            a4[f] = __builtin_amdgcn_mfma_f32_16x16x32_bf16(af, bv, a4[f], 0, 0, 0);
        }
    }
    float ln2 = lamn[t] * lamn[t], lb2 = lamb[t] * lamb[t];
#pragma unroll
    for (int f = 0; f < 5; ++f) {
        int c = (wv * 5 + f) * 16 + l15;
#pragma unroll
        for (int r = 0; r < 4; ++r) {
            int ng = n0 + lh * 4 + r;
            if (ng < 100) {
                size_t o = ((size_t)ng * NT + t) * NDIM + c;
                comb[o] = ln2 * sptn[o] + lb2 * a4[f][r];
            }
        }
    }
}

// ---------------------------------------------------------------- k_proto
__global__ __launch_bounds__(128) void k_proto(const float* __restrict__ comb,
    float* __restrict__ proto)
{
    int wt = blockIdx.x;
    int w = wt >> 3, t = wt & 7;
    int tid = threadIdx.x, lane = tid & 63, wv = tid >> 6;
    __shared__ float red[2];
    float mv[5]; float ss = 0.f;
#pragma unroll
    for (int m = 0; m < 5; ++m) {
        int c = tid + 128 * m;
        float a = 0.f;
#pragma unroll
        for (int s = 0; s < NSHOT; ++s)
            a += comb[(((size_t)(s * NWAY + w)) * NT + t) * NDIM + c];
        a *= 0.2f;
        mv[m] = a; ss += a * a;
    }
    ss = waveReduceSum(ss);
    if (lane == 0) red[wv] = ss;
    __syncthreads();
    float inv = invl2_(red[0] + red[1]);
#pragma unroll
    for (int m = 0; m < 5; ++m) proto[(size_t)wt * NDIM + tid + 128 * m] = mv[m] * inv;
}

// ---------------------------------------------------------------- k_act
// Barrier-free: per wave, B-fragments built directly from global qry columns;
// writes act [q][160 wt][128 xy] bf16 to global.
__global__ __launch_bounds__(512, 1) void k_act(const float* __restrict__ qry,
    const ushort* __restrict__ filtb, ushort* __restrict__ actb)
{
    int q = blockIdx.x;
    int tid = threadIdx.x, lane = tid & 63, wv = tid >> 6;     // 8 waves x 16 xy
    int l15 = lane & 15, lh = lane >> 4;
    const float* qbase = qry + (size_t)q * NDIM * NXY;
    int xy = wv * 16 + l15;
    const float* colb = qbase + (xy < NXY ? xy : 0);

    f32x4 acc[10];
#pragma unroll
    for (int m = 0; m < 10; ++m) acc[m] = (f32x4){0.f, 0.f, 0.f, 0.f};
    float ssq = 0.f;

    for (int c0 = 0; c0 < NDIM; c0 += 32) {
        float v[8];
#pragma unroll
        for (int j = 0; j < 8; ++j) {
            v[j] = colb[(size_t)(c0 + lh * 8 + j) * NXY];
            ssq += v[j] * v[j];
        }
        union { unsigned u[4]; s16x8 x; } bf;
#pragma unroll
        for (int p = 0; p < 4; ++p) bf.u[p] = pkbf_(v[2 * p], v[2 * p + 1]);
#pragma unroll
        for (int m = 0; m < 10; ++m) {
            s16x8 af = *(const s16x8*)&filtb[(size_t)(m * 16 + l15) * NDIM + c0 + lh * 8];
            acc[m] = __builtin_amdgcn_mfma_f32_16x16x32_bf16(af, bf.x, acc[m], 0, 0, 0);
        }
    }
    ssq += __shfl_xor(ssq, 16, 64);
    ssq += __shfl_xor(ssq, 32, 64);
    float inv = (xy < NXY) ? invl2_(ssq) : 0.f;

#pragma unroll
    for (int m = 0; m < 10; ++m) {
#pragma unroll
        for (int r = 0; r < 4; ++r) {
            int row = m * 16 + lh * 4 + r;
            float a = sigmoidf_(acc[m][r] * inv) * inv;
            actb[((size_t)q * NWT + row) * 128 + xy] = (ushort)bfr_(a);
        }
    }
}

// ---------------------------------------------------------------- k_pool
// Barrier-free pooling: A (act) fragments held in registers, B = qry rows (cvt),
// proto-dot + ssq folded; writes logits directly.
__global__ __launch_bounds__(320, 1) void k_pool(const float* __restrict__ qry,
    const ushort* __restrict__ actb, const float* __restrict__ proto,
    const float* __restrict__ wgt, float* __restrict__ out)
{
    int q = blockIdx.x;
    int tid = threadIdx.x, lane = tid & 63, wv = tid >> 6;     // 5 waves x 2 m-tiles
    int l15 = lane & 15, lh = lane >> 4;
    const float* qbase = qry + (size_t)q * NDIM * NXY;
    __shared__ float simacc[NWT * 2];
    __shared__ float simF[NWT];

    s16x8 af[2][4];
#pragma unroll
    for (int mi = 0; mi < 2; ++mi)
#pragma unroll
        for (int kk = 0; kk < 4; ++kk)
            af[mi][kk] = *(const s16x8*)&actb[((size_t)q * NWT + (wv * 2 + mi) * 16 + l15) * 128 + kk * 32 + lh * 8];

    float dacc[2][4], sacc[2][4];
#pragma unroll
    for (int mi = 0; mi < 2; ++mi)
#pragma unroll
        for (int r = 0; r < 4; ++r) { dacc[mi][r] = 0.f; sacc[mi][r] = 0.f; }

    for (int c0 = 0; c0 < NDIM; c0 += 64) {
#pragma unroll
        for (int ns = 0; ns < 4; ++ns) {
            int cb = c0 + ns * 16 + l15;
            const float* rp = qbase + (size_t)cb * NXY;
            s16x8 bfv[4];
#pragma unroll
            for (int kk = 0; kk < 4; ++kk) {
                if (kk == 3 && lh == 3) {
                    union { unsigned u[4]; s16x8 v; } r;
                    r.u[0] = pkbf_(rp[120], 0.f); r.u[1] = 0u; r.u[2] = 0u; r.u[3] = 0u;
                    bfv[kk] = r.v;
                } else {
                    bfv[kk] = cvt8_(rp + kk * 32 + lh * 8);
                }
            }
#pragma unroll
            for (int mi = 0; mi < 2; ++mi) {
                f32x4 c4 = (f32x4){0.f, 0.f, 0.f, 0.f};
#pragma unroll
                for (int kk = 0; kk < 4; ++kk)
                    c4 = __builtin_amdgcn_mfma_f32_16x16x32_bf16(af[mi][kk], bfv[kk], c4, 0, 0, 0);
#pragma unroll
                for (int r = 0; r < 4; ++r) {
                    int row = (wv * 2 + mi) * 16 + lh * 4 + r;
                    float p = proto[(size_t)row * NDIM + cb];
                    dacc[mi][r] += c4[r] * p;
                    sacc[mi][r] += c4[r] * c4[r];
                }
            }
        }
    }
#pragma unroll
    for (int mi = 0; mi < 2; ++mi) {
#pragma unroll
        for (int r = 0; r < 4; ++r) {
            float d = dacc[mi][r], s2 = sacc[mi][r];
#pragma unroll
            for (int off = 1; off < 16; off <<= 1) {
                d += __shfl_xor(d, off, 64);
                s2 += __shfl_xor(s2, off, 64);
            }
            if (l15 == 0) {
                int wt = (wv * 2 + mi) * 16 + lh * 4 + r;
                simacc[wt * 2 + 0] = d;
                simacc[wt * 2 + 1] = s2;
            }
        }
    }
    __syncthreads();
    if (tid < NWT) simF[tid] = simacc[tid * 2] * invl2_(simacc[tid * 2 + 1]);
    __syncthreads();
    if (tid < NWAY) {
        float lg = 0.f;
#pragma unroll
        for (int t = 0; t < NT; ++t) lg += simF[tid * NT + t] * wgt[tid * NT + t];
        out[q * NWAY + tid] = 2.0f * lg;   // / TEMP
    }
}

extern "C" void kernel_launch(void* const* d_in, const int* in_sizes, int n_in,
                              void* d_out, int out_size, void* d_ws, size_t ws_size,
                              hipStream_t stream)
{
    const float* spt  = (const float*)d_in[0];
    const float* qry  = (const float*)d_in[1];
    const float* l2v  = (const float*)d_in[2];
    const float* w1   = (const float*)d_in[3];
    const float* b1   = (const float*)d_in[4];
    const float* w2   = (const float*)d_in[5];
    const float* b2   = (const float*)d_in[6];
    const float* wb   = (const float*)d_in[7];
    const float* wq   = (const float*)d_in[8];
    const float* bq   = (const float*)d_in[9];
    const float* wk   = (const float*)d_in[10];
    const float* sat  = (const float*)d_in[11];
    const float* lamn = (const float*)d_in[12];
    const float* lamb = (const float*)d_in[13];
    const float* wt1  = (const float*)d_in[14];
    const float* bt1  = (const float*)d_in[15];
    const float* wt2  = (const float*)d_in[16];
    const float* bt2  = (const float*)d_in[17];
    const float* tb   = (const float*)d_in[18];
    const float* tl1  = (const float*)d_in[19];
    const float* tl2  = (const float*)d_in[20];

    float* ws = (float*)d_ws;
    ushort*  filtb  = (ushort*)ws;                       // 160*640 bf16      = 51200 f
    float*   wgt    = ws + 51200;                        // 160
    ushort*  wqb    = (ushort*)(ws + 51360);             // 8*640*640 bf16    = 1638400 f
    ushort*  wknb   = (ushort*)(ws + 51360 + 1638400);   // 8*384*640 bf16    = 983040 f
    ushort*  wbnT   = (ushort*)(ws + 2672800);           // 8*640*384 bf16    = 983040 f
    float*   invb   = ws + 3655840;                      // 2816
    ushort*  xb     = (ushort*)(ws + 3658656);           // 8*112*640 bf16    = 286720 f
    ushort*  qeb    = (ushort*)(ws + 3945376);           // 8*112*640 bf16    = 286720 f
    unsigned* attb  = (unsigned*)(ws + 4232096);         // 56*3072 uints     = 172032 f
    float*   sptn   = ws + 4404128;                      // 100*8*640         = 512000
    float*   combv  = ws + 4916128;                      // 512000
    float*   proto  = ws + 5428128;                      // 160*640           = 102400
    ushort*  actb   = (ushort*)(ws + 5530528);           // 1000*160*128 bf16 = 10240000 f
    float*   outp   = (float*)d_out;                     // total 15770528 f (~63 MB)

    hipLaunchKernelGGL(k_filt,     dim3(160),        dim3(256), 0, stream, l2v, w1, b1, w2, b2, filtb);
    hipLaunchKernelGGL(k_wgt,      dim3(20),         dim3(256), 0, stream, l2v, wt1, bt1, wt2, bt2, tb, tl1, tl2, wgt);
    hipLaunchKernelGGL(k_cvtwq,    dim3(1600),       dim3(256), 0, stream, wq, (unsigned*)wqb);
    hipLaunchKernelGGL(k_wknorm,   dim3(2808),       dim3(128), 0, stream, wk, wknb);
    hipLaunchKernelGGL(k_wbinv,    dim3(2808),       dim3(128), 0, stream, wb, invb);
    hipLaunchKernelGGL(k_wbT,      dim3(6, 10, 8),   dim3(256), 0, stream, wb, invb, (unsigned*)wbnT);
    hipLaunchKernelGGL(k_act,      dim3(1000),       dim3(512), 0, stream, qry, filtb, actb);
    hipLaunchKernelGGL(k_support2, dim3(20, 5),      dim3(512), 0, stream, spt, filtb, sptn, xb);
    hipLaunchKernelGGL(k_qe,       dim3(8, 7),       dim3(256), 0, stream, xb, wqb, bq, qeb);
    hipLaunchKernelGGL(k_att,      dim3(8, 7),       dim3(512), 0, stream, qeb, wknb, wbnT, attb, sptn, sat, lamn, lamb, combv);
    hipLaunchKernelGGL(k_proto,    dim3(160),        dim3(128), 0, stream, combv, proto);
    hipLaunchKernelGGL(k_pool,     dim3(1000),       dim3(320), 0, stream, qry, actb, proto, wgt, outp);
}

// Round 6
// 919.239 us; speedup vs baseline: 3.3288x; 1.0704x over previous
//
#include <hip/hip_runtime.h>
#include <hip/hip_bf16.h>

#define NWAY 20
#define NSHOT 5
#define NT 8
#define NDIM 640
#define NSEM 300
#define NSEMH 150
#define NCLS 351
#define NXY 121
#define NWT 160   // NWAY*NT, indexed wt = w*8 + t

typedef short s16x8 __attribute__((ext_vector_type(8)));
typedef float f32x4 __attribute__((ext_vector_type(4)));
typedef float f32x4u __attribute__((ext_vector_type(4), aligned(4)));

__device__ __forceinline__ float sigmoidf_(float x) { return 1.0f / (1.0f + expf(-x)); }
__device__ __forceinline__ float lreluf_(float x) { return x >= 0.0f ? x : 0.1f * x; }
__device__ __forceinline__ float invl2_(float ss) { return 1.0f / fmaxf(sqrtf(ss), 1e-12f); }

__device__ __forceinline__ unsigned bfr_(float f) {
    unsigned b = __float_as_uint(f);
    return (b + 0x7FFFu + ((b >> 16) & 1u)) >> 16;   // RNE to bf16
}
__device__ __forceinline__ unsigned pkbf_(float a, float b) { return bfr_(a) | (bfr_(b) << 16); }

__device__ __forceinline__ s16x8 cvt8_(const float* p) {
    f32x4u a = *(const f32x4u*)p;
    f32x4u b = *(const f32x4u*)(p + 4);
    union { unsigned u[4]; s16x8 v; } r;
    r.u[0] = pkbf_(a[0], a[1]); r.u[1] = pkbf_(a[2], a[3]);
    r.u[2] = pkbf_(b[0], b[1]); r.u[3] = pkbf_(b[2], b[3]);
    return r.v;
}

__device__ __forceinline__ float waveReduceSum(float v) {
#pragma unroll
    for (int off = 32; off > 0; off >>= 1) v += __shfl_down(v, off, 64);
    return v;
}

// ---------------------------------------------------------------- k_prepw
// merged: [0,1600) cvtwq | [1600,4408) wknorm | [4408,7216) wbinv | [7216,7376) filt | [7376,7396) wgt
__global__ __launch_bounds__(256) void k_prepw(const float* __restrict__ l2v,
    const float* __restrict__ w1, const float* __restrict__ b1,
    const float* __restrict__ w2, const float* __restrict__ b2,
    const float* __restrict__ wq, const float* __restrict__ wk,
    const float* __restrict__ wb, const float* __restrict__ wt1,
    const float* __restrict__ bt1, const float* __restrict__ wt2,
    const float* __restrict__ bt2, const float* __restrict__ tb,
    const float* __restrict__ tl1, const float* __restrict__ tl2,
    ushort* __restrict__ filtb, float* __restrict__ wgt,
    unsigned* __restrict__ wqb_u, ushort* __restrict__ wknb,
    float* __restrict__ invb)
{
    int b = blockIdx.x;
    int tid = threadIdx.x, lane = tid & 63, wv = tid >> 6;
    __shared__ float h_lds[NSEM];
    __shared__ float f_lds[NDIM];
    __shared__ float red4[4];
    __shared__ float h2[NSEMH];
    __shared__ float wl[NT];
    __shared__ float ssum;

    if (b < 1600) {
        size_t i = ((size_t)b * 256 + tid) * 8;
        const f32x4u a = *(const f32x4u*)(wq + i);
        const f32x4u c = *(const f32x4u*)(wq + i + 4);
        wqb_u[i / 2 + 0] = pkbf_(a[0], a[1]);
        wqb_u[i / 2 + 1] = pkbf_(a[2], a[3]);
        wqb_u[i / 2 + 2] = pkbf_(c[0], c[1]);
        wqb_u[i / 2 + 3] = pkbf_(c[2], c[3]);
        return;
    }
    if (b < 4408) {         // wknorm: r = t*351 + k
        int r = b - 1600;
        int t = r / NCLS, k = r - t * NCLS;
        const float* src = wk + (size_t)r * NDIM;
        float v0 = src[tid], v1 = src[tid + 256];
        bool h = tid < 128;
        float v2 = h ? src[tid + 512] : 0.f;
        float ss = v0 * v0 + v1 * v1 + v2 * v2;
        ss = waveReduceSum(ss);
        if (lane == 0) red4[wv] = ss;
        __syncthreads();
        float inv = invl2_(red4[0] + red4[1] + red4[2] + red4[3]);
        ushort* dst = wknb + ((size_t)t * 384 + k) * NDIM;
        dst[tid] = (ushort)bfr_(v0 * inv);
        dst[tid + 256] = (ushort)bfr_(v1 * inv);
        if (h) dst[tid + 512] = (ushort)bfr_(v2 * inv);
        return;
    }
    if (b < 7216) {         // wbinv: r = k*8 + t
        int r = b - 4408;
        const float* src = wb + (size_t)r * NDIM;
        float v0 = src[tid], v1 = src[tid + 256];
        float v2 = (tid < 128) ? src[tid + 512] : 0.f;
        float ss = v0 * v0 + v1 * v1 + v2 * v2;
        ss = waveReduceSum(ss);
        if (lane == 0) red4[wv] = ss;
        __syncthreads();
        if (tid == 0) invb[r] = invl2_(red4[0] + red4[1] + red4[2] + red4[3]);
        return;
    }
    if (b < 7376) {         // filt
        int wt = b - 7216;
        int w = wt >> 3, t = wt & 7;
        for (int j = 0; j < 75; ++j) {
            int d = wv * 75 + j;
            float acc = 0.f;
#pragma unroll
            for (int m = 0; m < 5; ++m) {
                int s = lane + 64 * m;
                if (s < NSEM) acc += l2v[w * NSEM + s] * w1[((size_t)t * NSEM + d) * NSEM + s];
            }
            acc = waveReduceSum(acc);
            if (lane == 0) h_lds[d] = lreluf_(acc + b1[t * NSEM + d]);
        }
        __syncthreads();
        for (int j = 0; j < 160; ++j) {
            int c = wv * 160 + j;
            float acc = 0.f;
#pragma unroll
            for (int m = 0; m < 5; ++m) {
                int d = lane + 64 * m;
                if (d < NSEM) acc += h_lds[d] * w2[((size_t)t * NDIM + c) * NSEM + d];
            }
            acc = waveReduceSum(acc);
            if (lane == 0) f_lds[c] = acc + b2[t * NDIM + c];
        }
        __syncthreads();
        float s = 0.f;
        for (int c = tid; c < NDIM; c += 256) s += f_lds[c] * f_lds[c];
        s = waveReduceSum(s);
        if (lane == 0) red4[wv] = s;
        __syncthreads();
        float inv = invl2_(red4[0] + red4[1] + red4[2] + red4[3]);
        for (int c = tid; c < NDIM; c += 256)
            filtb[(size_t)wt * NDIM + c] = (ushort)bfr_(f_lds[c] * inv);
        return;
    }
    {                       // wgt
        int w = b - 7376;
        if (tid < NSEMH) {
            float acc = 0.f;
            for (int s = 0; s < NSEM; ++s) acc += l2v[w * NSEM + s] * wt1[tid * NSEM + s];
            h2[tid] = lreluf_(acc + bt1[tid]);
        }
        __syncthreads();
        if (tid < NT) {
            float acc = 0.f;
            for (int d = 0; d < NSEMH; ++d) acc += h2[d] * wt2[tid * NSEMH + d];
            float wg = sigmoidf_(acc + bt2[tid]);
            wl[tid] = tl1[0] * tl1[0] * sigmoidf_(tb[tid]) + tl2[0] * tl2[0] * wg;
        }
        __syncthreads();
        if (tid == 0) { float s2 = 0.f; for (int t = 0; t < NT; ++t) s2 += wl[t]; ssum = s2; }
        __syncthreads();
        if (tid < NT) wgt[w * NT + tid] = wl[tid] / ssum;
    }
}

// ---------------------------------------------------------------- k_wbT : wbn^T bf16 [t][c 640][k 384pad]
__global__ __launch_bounds__(256) void k_wbT(const float* __restrict__ wb,
    const float* __restrict__ invb, unsigned* __restrict__ wbnT_u)
{
    int k0 = blockIdx.x * 64, c0 = blockIdx.y * 64, t = blockIdx.z;
    int tid = threadIdx.x;
    __shared__ float tile[64][65];
    __shared__ float invT[64];
    {
        int i = tid >> 2, q = tid & 3;
        int kg = min(k0 + i, NCLS - 1);
#pragma unroll
        for (int u = 0; u < 4; ++u) {
            int c = q * 16 + u * 4;
            f32x4u v = *(const f32x4u*)(wb + ((size_t)kg * NT + t) * NDIM + c0 + c);
            tile[i][c] = v[0]; tile[i][c + 1] = v[1]; tile[i][c + 2] = v[2]; tile[i][c + 3] = v[3];
        }
        if (tid < 64) {
            int kg2 = k0 + tid;
            invT[tid] = (kg2 < NCLS) ? invb[(size_t)kg2 * NT + t] : 0.f;
        }
    }
    __syncthreads();
    int cc = tid >> 2, qq = tid & 3;
    size_t rowo = (((size_t)t * NDIM + c0 + cc) * 384 + k0) / 2;
#pragma unroll
    for (int u = 0; u < 8; ++u) {
        int kl = qq * 16 + u * 2;
        float v0 = tile[kl][cc] * invT[kl];
        float v1 = tile[kl + 1][cc] * invT[kl + 1];
        wbnT_u[rowo + qq * 8 + u] = pkbf_(v0, v1);
    }
}

// ---------------------------------------------------------------- k_support2
__global__ __launch_bounds__(512) void k_support2(const float* __restrict__ spt,
    const ushort* __restrict__ filtb, float* __restrict__ sptn,
    ushort* __restrict__ xb)
{
    int w = blockIdx.x, s = blockIdx.y;
    int n = s * NWAY + w;
    int tid = threadIdx.x, lane = tid & 63, wv = tid >> 6;     // 8 waves
    int l15 = lane & 15, lh = lane >> 4;
    const float* base = spt + (size_t)n * NDIM * NXY;

    __shared__ unsigned actL[16 * 64];
    __shared__ float redT[8 * 8];
    __shared__ float invt[8];

    for (int i = tid; i < 16 * 64; i += 512) actL[i] = 0u;

    int xy = wv * 16 + l15;
    const float* colb = base + (xy < NXY ? xy : 0);
    const ushort* arow1 = filtb + (size_t)(w * NT + (l15 & 7)) * NDIM + lh * 8;
    f32x4 acc = {0.f, 0.f, 0.f, 0.f};
    float ssq = 0.f;
    for (int c0 = 0; c0 < NDIM; c0 += 32) {
        float v[8];
#pragma unroll
        for (int j = 0; j < 8; ++j) {
            v[j] = colb[(size_t)(c0 + lh * 8 + j) * NXY];
            ssq += v[j] * v[j];
        }
        union { unsigned u[4]; s16x8 x; } bf;
#pragma unroll
        for (int p = 0; p < 4; ++p) bf.u[p] = pkbf_(v[2 * p], v[2 * p + 1]);
        s16x8 af = *(const s16x8*)(arow1 + c0);
        acc = __builtin_amdgcn_mfma_f32_16x16x32_bf16(af, bf.x, acc, 0, 0, 0);
    }
    ssq += __shfl_xor(ssq, 16, 64);
    ssq += __shfl_xor(ssq, 32, 64);
    float inv = (xy < NXY) ? invl2_(ssq) : 0.f;
    __syncthreads();
#pragma unroll
    for (int r = 0; r < 4; ++r) {
        int row = lh * 4 + r;
        if (row < 8) {
            float a = sigmoidf_(acc[r] * inv) * inv;
            unsigned g = ((unsigned)(xy >> 3) ^ (unsigned)row) & 15u;
            *(ushort*)((char*)actL + (size_t)row * 256 + g * 16 + (xy & 7) * 2) = (ushort)bfr_(a);
        }
    }
    __syncthreads();

    f32x4 acc2[5];
#pragma unroll
    for (int f = 0; f < 5; ++f) acc2[f] = (f32x4){0.f, 0.f, 0.f, 0.f};
#pragma unroll
    for (int ks = 0; ks < 4; ++ks) {
        int xyb = ks * 32 + lh * 8;
        unsigned g = ((unsigned)(ks * 4 + lh) ^ (unsigned)l15) & 15u;
        s16x8 af = *(const s16x8*)&actL[l15 * 64 + g * 4];
#pragma unroll
        for (int f = 0; f < 5; ++f) {
            int c = (wv * 5 + f) * 16 + l15;
            const float* rp = base + (size_t)c * NXY;
            s16x8 bfv;
            if (ks == 3 && lh == 3) {
                union { unsigned u[4]; s16x8 v; } r;
                r.u[0] = pkbf_(rp[120], 0.f); r.u[1] = 0u; r.u[2] = 0u; r.u[3] = 0u;
                bfv = r.v;
            } else {
                bfv = cvt8_(rp + xyb);
            }
            acc2[f] = __builtin_amdgcn_mfma_f32_16x16x32_bf16(af, bfv, acc2[f], 0, 0, 0);
        }
    }
    {
        float pr[4] = {0.f, 0.f, 0.f, 0.f};
#pragma unroll
        for (int f = 0; f < 5; ++f)
#pragma unroll
            for (int r = 0; r < 4; ++r) pr[r] += acc2[f][r] * acc2[f][r];
#pragma unroll
        for (int r = 0; r < 4; ++r) {
#pragma unroll
            for (int off = 1; off < 16; off <<= 1) pr[r] += __shfl_xor(pr[r], off, 64);
        }
        if (l15 == 0 && lh < 2) {
#pragma unroll
            for (int r = 0; r < 4; ++r) redT[wv * 8 + lh * 4 + r] = pr[r];
        }
    }
    __syncthreads();
    if (tid < 8) {
        float s8 = 0.f;
#pragma unroll
        for (int w8 = 0; w8 < 8; ++w8) s8 += redT[w8 * 8 + tid];
        invt[tid] = invl2_(s8);
    }
    __syncthreads();
    if (lh < 2) {
#pragma unroll
        for (int f = 0; f < 5; ++f) {
            int c = (wv * 5 + f) * 16 + l15;
#pragma unroll
            for (int r = 0; r < 4; ++r) {
                int t = lh * 4 + r;
                float val = acc2[f][r] * invt[t];
                sptn[((size_t)n * NT + t) * NDIM + c] = val;
                xb[((size_t)t * 112 + n) * NDIM + c] = (ushort)bfr_(val);
            }
        }
    }
}

// ---------------------------------------------------------------- k_qatt (fused qe + att)
__global__ __launch_bounds__(512) void k_qatt(const ushort* __restrict__ xb,
    const ushort* __restrict__ wqb, const float* __restrict__ bq,
    const ushort* __restrict__ wknb, const ushort* __restrict__ wbnT,
    const float* __restrict__ sptn, const float* __restrict__ scale_att,
    const float* __restrict__ lamn, const float* __restrict__ lamb,
    float* __restrict__ comb)
{
    int t = blockIdx.x, mt = blockIdx.y, n0 = mt * 16;
    int tid = threadIdx.x, lane = tid & 63, wv = tid >> 6;     // 8 waves
    int l15 = lane & 15, lh = lane >> 4;
    __shared__ __align__(16) ushort qebL[16 * 640];            // swizzled (20 KB)
    __shared__ float scL[16 * 384];                            // 24 KB
    __shared__ __align__(16) unsigned attL[16 * 192];          // swizzled bf16 (12 KB)
    __shared__ float redQ[8 * 16];
    __shared__ float invR[16];

    // ---- phase Q: QE = X @ wq^T + bq, l2n rows ----
    f32x4 acc[5];
#pragma unroll
    for (int f = 0; f < 5; ++f) acc[f] = (f32x4){0.f, 0.f, 0.f, 0.f};
    float bqv[5];
#pragma unroll
    for (int f = 0; f < 5; ++f) bqv[f] = bq[t * NDIM + (wv * 5 + f) * 16 + l15];
    const ushort* arow = xb + ((size_t)t * 112 + n0 + l15) * NDIM + lh * 8;
    for (int k0 = 0; k0 < NDIM; k0 += 32) {
        s16x8 af = *(const s16x8*)(arow + k0);
#pragma unroll
        for (int f = 0; f < 5; ++f) {
            int d = (wv * 5 + f) * 16 + l15;
            s16x8 bv = *(const s16x8*)&wqb[((size_t)t * NDIM + d) * NDIM + k0 + lh * 8];
            acc[f] = __builtin_amdgcn_mfma_f32_16x16x32_bf16(af, bv, acc[f], 0, 0, 0);
        }
    }
    {
        float pr[4] = {0.f, 0.f, 0.f, 0.f};
#pragma unroll
        for (int f = 0; f < 5; ++f)
#pragma unroll
            for (int r = 0; r < 4; ++r) { float qv = acc[f][r] + bqv[f]; pr[r] += qv * qv; }
#pragma unroll
        for (int r = 0; r < 4; ++r) {
#pragma unroll
            for (int off = 1; off < 16; off <<= 1) pr[r] += __shfl_xor(pr[r], off, 64);
        }
        if (l15 == 0) {
#pragma unroll
            for (int r = 0; r < 4; ++r) redQ[wv * 16 + lh * 4 + r] = pr[r];
        }
    }
    __syncthreads();
    if (tid < 16) {
        float s = 0.f;
#pragma unroll
        for (int w8 = 0; w8 < 8; ++w8) s += redQ[w8 * 16 + tid];
        invR[tid] = invl2_(s);
    }
    __syncthreads();
#pragma unroll
    for (int f = 0; f < 5; ++f) {
        int d = (wv * 5 + f) * 16 + l15;
        unsigned g = (unsigned)(d >> 3);
        unsigned gh = g & ~15u, gl = g & 15u;
#pragma unroll
        for (int r = 0; r < 4; ++r) {
            int nn = lh * 4 + r;
            float qv = (acc[f][r] + bqv[f]) * invR[nn];
            unsigned gs = gh | (gl ^ (unsigned)nn);
            qebL[nn * 640 + gs * 8 + (d & 7)] = (ushort)bfr_(qv);
        }
    }
    __syncthreads();

    // ---- phase S: scores = scale * QE @ wkn^T ----
    f32x4 a3[3];
#pragma unroll
    for (int f = 0; f < 3; ++f) a3[f] = (f32x4){0.f, 0.f, 0.f, 0.f};
    for (int k0 = 0; k0 < NDIM; k0 += 32) {
        unsigned g = (unsigned)((k0 >> 3) + lh);
        unsigned gs = (g & ~15u) | ((g & 15u) ^ (unsigned)l15);
        s16x8 af = *(const s16x8*)&qebL[l15 * 640 + gs * 8];
#pragma unroll
        for (int f = 0; f < 3; ++f) {
            int kk = (wv * 3 + f) * 16 + l15;
            s16x8 bv = *(const s16x8*)&wknb[((size_t)t * 384 + kk) * NDIM + k0 + lh * 8];
            a3[f] = __builtin_amdgcn_mfma_f32_16x16x32_bf16(af, bv, a3[f], 0, 0, 0);
        }
    }
    float sat = scale_att[t];
#pragma unroll
    for (int f = 0; f < 3; ++f) {
        int kk = (wv * 3 + f) * 16 + l15;
#pragma unroll
        for (int r = 0; r < 4; ++r) scL[(lh * 4 + r) * 384 + kk] = sat * a3[f][r];
    }
    __syncthreads();
    {   // softmax: 16 rows x 32 threads
        int row = tid >> 5, li = tid & 31;
        float e[12]; float mx = -1e30f;
#pragma unroll
        for (int j = 0; j < 12; ++j) {
            int k = li + 32 * j;
            float v = (k < NCLS) ? scL[row * 384 + k] : -1e30f;
            e[j] = v; mx = fmaxf(mx, v);
        }
#pragma unroll
        for (int off = 1; off < 32; off <<= 1) mx = fmaxf(mx, __shfl_xor(mx, off, 64));
        float se = 0.f;
#pragma unroll
        for (int j = 0; j < 12; ++j) {
            int k = li + 32 * j;
            float ev = (k < NCLS) ? expf(e[j] - mx) : 0.f;
            e[j] = ev; se += ev;
        }
#pragma unroll
        for (int off = 1; off < 32; off <<= 1) se += __shfl_xor(se, off, 64);
        float is = 1.f / se;
#pragma unroll
        for (int j = 0; j < 12; ++j) scL[row * 384 + li + 32 * j] = e[j] * is;
    }
    __syncthreads();
    // pack att -> attL bf16 swizzled
    for (int idx = tid; idx < 3072; idx += 512) {
        int row = idx / 192, pp = idx - row * 192;
        int k2 = 2 * pp;
        unsigned g = (unsigned)(k2 >> 3);
        unsigned gs = (g & ~15u) | ((g & 15u) ^ (unsigned)row);
        attL[row * 192 + gs * 4 + ((k2 >> 1) & 3)] = pkbf_(scL[row * 384 + k2], scL[row * 384 + k2 + 1]);
    }
    __syncthreads();

    // ---- phase W: wtb = att @ wbnT ; comb epilogue ----
    f32x4 a4[5];
#pragma unroll
    for (int f = 0; f < 5; ++f) a4[f] = (f32x4){0.f, 0.f, 0.f, 0.f};
    const ushort* attp = (const ushort*)attL;
    for (int k0 = 0; k0 < 384; k0 += 32) {
        unsigned g = (unsigned)((k0 >> 3) + lh);
        unsigned gs = (g & ~15u) | ((g & 15u) ^ (unsigned)l15);
        s16x8 af = *(const s16x8*)&attp[l15 * 384 + gs * 8];
#pragma unroll
        for (int f = 0; f < 5; ++f) {
            int c = (wv * 5 + f) * 16 + l15;
            s16x8 bv = *(const s16x8*)&wbnT[((size_t)t * NDIM + c) * 384 + k0 + lh * 8];
            a4[f] = __builtin_amdgcn_mfma_f32_16x16x32_bf16(af, bv, a4[f], 0, 0, 0);
        }
    }
    float ln2 = lamn[t] * lamn[t], lb2 = lamb[t] * lamb[t];
#pragma unroll
    for (int f = 0; f < 5; ++f) {
        int c = (wv * 5 + f) * 16 + l15;
#pragma unroll
        for (int r = 0; r < 4; ++r) {
            int ng = n0 + lh * 4 + r;
            if (ng < 100) {
                size_t o = ((size_t)ng * NT + t) * NDIM + c;
                comb[o] = ln2 * sptn[o] + lb2 * a4[f][r];
            }
        }
    }
}

// ---------------------------------------------------------------- k_proto
__global__ __launch_bounds__(128) void k_proto(const float* __restrict__ comb,
    float* __restrict__ proto)
{
    int wt = blockIdx.x;
    int w = wt >> 3, t = wt & 7;
    int tid = threadIdx.x, lane = tid & 63, wv = tid >> 6;
    __shared__ float red[2];
    float mv[5]; float ss = 0.f;
#pragma unroll
    for (int m = 0; m < 5; ++m) {
        int c = tid + 128 * m;
        float a = 0.f;
#pragma unroll
        for (int s = 0; s < NSHOT; ++s)
            a += comb[(((size_t)(s * NWAY + w)) * NT + t) * NDIM + c];
        a *= 0.2f;
        mv[m] = a; ss += a * a;
    }
    ss = waveReduceSum(ss);
    if (lane == 0) red[wv] = ss;
    __syncthreads();
    float inv = invl2_(red[0] + red[1]);
#pragma unroll
    for (int m = 0; m < 5; ++m) proto[(size_t)wt * NDIM + tid + 128 * m] = mv[m] * inv;
}

// ---------------------------------------------------------------- k_qprep
// Per query: bf16 transpose qbT[ql][128 xy][640 c] (unnormalized) + invL[q][128].
__global__ __launch_bounds__(512) void k_qprep(const float* __restrict__ qry,
    ushort* __restrict__ qbT, float* __restrict__ invL, int q0)
{
    int ql = blockIdx.x; int q = q0 + ql;
    int tid = threadIdx.x;
    int xy = tid & 127, cl = tid >> 7;     // cl 0..3
    const float* base = qry + (size_t)q * NDIM * NXY;
    bool vx = xy < NXY;
    __shared__ ushort tile[128][68];
    __shared__ float ssq4[4][128];
    float ss = 0.f;
    ushort* outT = qbT + (size_t)ql * 128 * NDIM;
    for (int ct = 0; ct < NDIM; ct += 64) {
#pragma unroll
        for (int j = 0; j < 16; ++j) {
            int c = ct + cl * 16 + j;
            float v = vx ? base[(size_t)c * NXY + xy] : 0.f;
            ss += v * v;
            tile[xy][cl * 16 + j] = (ushort)bfr_(v);
        }
        __syncthreads();
#pragma unroll
        for (int jj = 0; jj < 8; ++jj) {
            int row = (tid >> 5) + 16 * jj;
            int cc = tid & 31;
            unsigned val = *(const unsigned*)&tile[row][cc * 2];
            *(unsigned*)&outT[(size_t)row * NDIM + ct + cc * 2] = val;
        }
        __syncthreads();
    }
    ssq4[cl][xy] = ss;
    __syncthreads();
    if (tid < 128) {
        float s = ssq4[0][tid] + ssq4[1][tid] + ssq4[2][tid] + ssq4[3][tid];
        invL[(size_t)q * 128 + tid] = (tid < NXY) ? invl2_(s) : 0.f;
    }
}

// ---------------------------------------------------------------- k_query2 (fused act + pool + sim)
__global__ __launch_bounds__(512, 1) void k_query2(const float* __restrict__ qry,
    const ushort* __restrict__ qbT, const float* __restrict__ invL,
    const ushort* __restrict__ filtb, const float* __restrict__ proto,
    const float* __restrict__ wgt, float* __restrict__ out, int q0)
{
    int ql = blockIdx.x; int q = q0 + ql;
    int tid = threadIdx.x, lane = tid & 63, wv = tid >> 6;     // 8 waves
    int l15 = lane & 15, lh = lane >> 4;
    const float* qbase = qry + (size_t)q * NDIM * NXY;
    __shared__ __align__(16) unsigned actL[160 * 64];          // 40 KB swizzled
    __shared__ float simacc[8 * NWT * 2];                      // 10 KB
    __shared__ float simF[NWT];

    // ---------------- phase 1: act' ----------------
    f32x4 acc[10];
#pragma unroll
    for (int m = 0; m < 10; ++m) acc[m] = (f32x4){0.f, 0.f, 0.f, 0.f};
    int xy = wv * 16 + l15;
    const ushort* brow = qbT + ((size_t)ql * 128 + xy) * NDIM + lh * 8;
    for (int c0 = 0; c0 < NDIM; c0 += 32) {
        s16x8 bf = *(const s16x8*)(brow + c0);
#pragma unroll
        for (int m = 0; m < 10; ++m) {
            s16x8 af = *(const s16x8*)&filtb[(size_t)(m * 16 + l15) * NDIM + c0 + lh * 8];
            acc[m] = __builtin_amdgcn_mfma_f32_16x16x32_bf16(af, bf, acc[m], 0, 0, 0);
        }
    }
    float inv = invL[(size_t)q * 128 + xy];
    for (int i = tid; i < 8 * NWT * 2; i += 512) simacc[i] = 0.f;
    {
        unsigned xg = (unsigned)(xy >> 3);
        unsigned xo = (unsigned)(xy & 7) * 2;
#pragma unroll
        for (int m = 0; m < 10; ++m) {
#pragma unroll
            for (int r = 0; r < 4; ++r) {
                int row = m * 16 + lh * 4 + r;
                float a = sigmoidf_(acc[m][r] * inv) * inv;   // act' (B in phase 2 is RAW qry)
                unsigned g = xg ^ (unsigned)(row & 15);
                *(ushort*)((char*)actL + (size_t)row * 256 + g * 16 + xo) = (ushort)bfr_(a);
            }
        }
    }
    __syncthreads();

    // ---------------- phase 2: pool + sim ----------------
    int ns = wv & 3, a_ = wv >> 2;
    float dacc[5][4], sacc[5][4];
#pragma unroll
    for (int i = 0; i < 5; ++i)
#pragma unroll
        for (int r = 0; r < 4; ++r) { dacc[i][r] = 0.f; sacc[i][r] = 0.f; }

    for (int c0 = 0; c0 < NDIM; c0 += 64) {
        int cb = c0 + ns * 16 + l15;
        const float* rp = qbase + (size_t)cb * NXY;
        s16x8 bfv[4];
#pragma unroll
        for (int kk = 0; kk < 4; ++kk) {
            if (kk == 3 && lh == 3) {
                union { unsigned u[4]; s16x8 v; } r;
                r.u[0] = pkbf_(rp[120], 0.f); r.u[1] = 0u; r.u[2] = 0u; r.u[3] = 0u;
                bfv[kk] = r.v;
            } else {
                bfv[kk] = cvt8_(rp + kk * 32 + lh * 8);
            }
        }
#pragma unroll
        for (int i = 0; i < 5; ++i) {
            int m = a_ + 2 * i;
            f32x4 c4 = (f32x4){0.f, 0.f, 0.f, 0.f};
#pragma unroll
            for (int kk = 0; kk < 4; ++kk) {
                unsigned g = ((unsigned)(kk * 4 + lh) ^ (unsigned)l15) & 15u;
                s16x8 af = *(const s16x8*)&actL[(m * 16 + l15) * 64 + g * 4];
                c4 = __builtin_amdgcn_mfma_f32_16x16x32_bf16(af, bfv[kk], c4, 0, 0, 0);
            }
#pragma unroll
            for (int r = 0; r < 4; ++r) {
                float p = proto[(size_t)(m * 16 + lh * 4 + r) * NDIM + cb];
                dacc[i][r] += c4[r] * p;
                sacc[i][r] += c4[r] * c4[r];
            }
        }
    }
#pragma unroll
    for (int i = 0; i < 5; ++i) {
#pragma unroll
        for (int r = 0; r < 4; ++r) {
            float d = dacc[i][r], s2 = sacc[i][r];
#pragma unroll
            for (int off = 1; off < 16; off <<= 1) {
                d += __shfl_xor(d, off, 64);
                s2 += __shfl_xor(s2, off, 64);
            }
            if (l15 == 0) {
                int wt = (a_ + 2 * i) * 16 + lh * 4 + r;
                simacc[(wv * NWT + wt) * 2 + 0] = d;
                simacc[(wv * NWT + wt) * 2 + 1] = s2;
            }
        }
    }
    __syncthreads();
    if (tid < NWT) {
        float d = 0.f, s2 = 0.f;
#pragma unroll
        for (int w8 = 0; w8 < 8; ++w8) {
            d += simacc[(w8 * NWT + tid) * 2 + 0];
            s2 += simacc[(w8 * NWT + tid) * 2 + 1];
        }
        simF[tid] = d * invl2_(s2);
    }
    __syncthreads();
    if (tid < NWAY) {
        float lg = 0.f;
#pragma unroll
        for (int t = 0; t < NT; ++t) lg += simF[tid * NT + t] * wgt[tid * NT + t];
        out[q * NWAY + tid] = 2.0f * lg;   // / TEMP
    }
}

extern "C" void kernel_launch(void* const* d_in, const int* in_sizes, int n_in,
                              void* d_out, int out_size, void* d_ws, size_t ws_size,
                              hipStream_t stream)
{
    const float* spt  = (const float*)d_in[0];
    const float* qry  = (const float*)d_in[1];
    const float* l2v  = (const float*)d_in[2];
    const float* w1   = (const float*)d_in[3];
    const float* b1   = (const float*)d_in[4];
    const float* w2   = (const float*)d_in[5];
    const float* b2   = (const float*)d_in[6];
    const float* wb   = (const float*)d_in[7];
    const float* wq   = (const float*)d_in[8];
    const float* bq   = (const float*)d_in[9];
    const float* wk   = (const float*)d_in[10];
    const float* sat  = (const float*)d_in[11];
    const float* lamn = (const float*)d_in[12];
    const float* lamb = (const float*)d_in[13];
    const float* wt1  = (const float*)d_in[14];
    const float* bt1  = (const float*)d_in[15];
    const float* wt2  = (const float*)d_in[16];
    const float* bt2  = (const float*)d_in[17];
    const float* tb   = (const float*)d_in[18];
    const float* tl1  = (const float*)d_in[19];
    const float* tl2  = (const float*)d_in[20];

    float* ws = (float*)d_ws;
    ushort*  filtb  = (ushort*)ws;                 // 51,200 f
    float*   wgt    = ws + 51200;                  // 160
    ushort*  wqb    = (ushort*)(ws + 51360);       // 1,638,400 f
    ushort*  wknb   = (ushort*)(ws + 1689760);     // 983,040 f
    ushort*  wbnT   = (ushort*)(ws + 2672800);     // 983,040 f
    float*   invb   = ws + 3655840;                // 2,816
    ushort*  xb     = (ushort*)(ws + 3658656);     // 286,720 f
    float*   sptn   = ws + 3945376;                // 512,000
    float*   combv  = ws + 4457376;                // 512,000
    float*   proto  = ws + 4969376;                // 102,400
    float*   invL   = ws + 5071776;                // 128,000
    ushort*  qbT    = (ushort*)(ws + 5199776);     // 500*128*640 bf16 = 20,480,000 f
    float*   outp   = (float*)d_out;               // total ~25.7M floats (~103 MB)

    hipLaunchKernelGGL(k_prepw,    dim3(7396),     dim3(256), 0, stream,
                       l2v, w1, b1, w2, b2, wq, wk, wb, wt1, bt1, wt2, bt2, tb, tl1, tl2,
                       filtb, wgt, (unsigned*)wqb, wknb, invb);
    hipLaunchKernelGGL(k_wbT,      dim3(6, 10, 8), dim3(256), 0, stream, wb, invb, (unsigned*)wbnT);
    hipLaunchKernelGGL(k_support2, dim3(20, 5),    dim3(512), 0, stream, spt, filtb, sptn, xb);
    hipLaunchKernelGGL(k_qatt,     dim3(8, 7),     dim3(512), 0, stream,
                       xb, wqb, bq, wknb, wbnT, sptn, sat, lamn, lamb, combv);
    hipLaunchKernelGGL(k_proto,    dim3(160),      dim3(128), 0, stream, combv, proto);
    for (int ch = 0; ch < 2; ++ch) {
        int q0 = ch * 500;
        hipLaunchKernelGGL(k_qprep,  dim3(500), dim3(512), 0, stream, qry, qbT, invL, q0);
        hipLaunchKernelGGL(k_query2, dim3(500), dim3(512), 0, stream,
                           qry, qbT, invL, filtb, proto, wgt, outp, q0);
    }
}